// Round 16
// baseline (263.173 us; speedup 1.0000x reference)
//
#include <hip/hip_runtime.h>
#include <cstdint>
#include <type_traits>

// ---------------- common types / helpers ----------------
typedef __attribute__((ext_vector_type(8))) short bf16x8;   // 8 bf16 in 4 VGPRs
typedef __attribute__((ext_vector_type(4))) float f32x4;

typedef unsigned int __attribute__((address_space(1))) as1_uint;
typedef unsigned int __attribute__((address_space(3))) as3_uint;

__device__ __forceinline__ void llds16(const void* g, void* l) {
  // async global->LDS, 16B per lane; LDS dst is wave-uniform base + lane*16
  __builtin_amdgcn_global_load_lds((const as1_uint*)g, (as3_uint*)l, 16, 0, 0);
}

__device__ __forceinline__ unsigned short f2bf(float f) {
  unsigned int u = __builtin_bit_cast(unsigned int, f);
  u = (u + 0x7fffu + ((u >> 16) & 1u)) >> 16;   // RNE
  return (unsigned short)u;
}
__device__ __forceinline__ float bf2f(unsigned short h) {
  unsigned int u = ((unsigned int)h) << 16;
  return __builtin_bit_cast(float, u);
}

#define MEMBAR() asm volatile("" ::: "memory")

// ---------------- elementwise convert f32 -> bf16 ----------------
__global__ __launch_bounds__(256) void cvt_f32_bf16(const float* __restrict__ in,
                                                    unsigned short* __restrict__ out, int n4) {
  int i = blockIdx.x * blockDim.x + threadIdx.x;
  int stride = gridDim.x * blockDim.x;
  for (; i < n4; i += stride) {
    float4 v = ((const float4*)in)[i];
    uint2 p;
    p.x = (unsigned)f2bf(v.x) | ((unsigned)f2bf(v.y) << 16);
    p.y = (unsigned)f2bf(v.z) | ((unsigned)f2bf(v.w) << 16);
    ((uint2*)out)[i] = p;
  }
}

// ---------------- transpose + convert: W[K][N] f32 -> Wt[N][K] bf16 ----------------
__global__ __launch_bounds__(256) void transpose_f32_bf16(const float* __restrict__ W,
                                                          unsigned short* __restrict__ Wt,
                                                          int K, int N) {
  __shared__ float tile[64][65];
  int n0 = blockIdx.x * 64, k0 = blockIdx.y * 64;
  int t = threadIdx.x;
  int lr = t >> 4, lc = (t & 15) * 4;
#pragma unroll
  for (int i = 0; i < 4; ++i) {
    int k = lr + i * 16;
    float4 v = *(const float4*)&W[(size_t)(k0 + k) * N + n0 + lc];
    tile[k][lc] = v.x; tile[k][lc + 1] = v.y; tile[k][lc + 2] = v.z; tile[k][lc + 3] = v.w;
  }
  __syncthreads();
  int n = t >> 2, kc = (t & 3) * 16;
  unsigned short* dst = &Wt[(size_t)(n0 + n) * K + k0 + kc];
#pragma unroll
  for (int j = 0; j < 16; ++j) dst[j] = f2bf(tile[kc + j][n]);
}

// ---------------- RoPE tables (TRANSPOSED): cos/sin [32][2048] ----------------
__global__ __launch_bounds__(256) void rope_tabT(float* __restrict__ cosT, float* __restrict__ sinT) {
  int i = blockIdx.x * 256 + threadIdx.x;  // < 32*2048
  int dm = i >> 11, t = i & 2047;
  float inv = powf(10000.0f, -(float)dm * (1.0f / 32.0f));
  float a = (float)t * inv;
  cosT[i] = cosf(a);
  sinT[i] = sinf(a);
}

// B-panel-hot XCD block mapping (requires gridDim.y % 8 == 0)
__device__ __forceinline__ void block_map(int& bx, int& by) {
  const int lin = blockIdx.y * gridDim.x + blockIdx.x;
  const int xcd = lin & 7;
  const int idx = lin >> 3;
  const int ych = gridDim.y >> 3;
  by = xcd * ych + (idx & (ych - 1));
  bx = idx / ych;
}

// ---------------- ring-3 NT GEMM (proj): C[M][N] = A[M][K] * Bt[N][K]^T --------------
// vmcnt(4) steady-state; vmcnt(0) on the FINAL iteration.
template <typename OutT>
__global__ __launch_bounds__(256) void gemm_ring(const unsigned short* __restrict__ A,
                                                 const unsigned short* __restrict__ Bt,
                                                 OutT* __restrict__ C, int M, int N, int K) {
  __shared__ unsigned short As[3][128 * 32];
  __shared__ unsigned short Bs[3][128 * 32];
  const int tid = threadIdx.x;
  const int w = tid >> 6, lane = tid & 63;
  const int l15 = lane & 15, lg = lane >> 4;
  const int wr = w >> 1, wc = w & 1;

  int bx, by;
  block_map(bx, by);
  const int m0 = by * 128, n0 = bx * 128;

  const size_t K2 = (size_t)K * 2;
  const char* Ag = (const char*)A;
  const char* Bg = (const char*)Bt;
  const int rc = lane >> 2;            // row within chunk 0..15
  const int cb = (lane & 3) * 16;      // byte col within row

  auto stage = [&](int buf, int kt) {
#pragma unroll
    for (int i = 0; i < 2; ++i) {
      int c = w + i * 4;
      int row = c * 16 + rc;
      int srcc = cb ^ (((row >> 1) & 3) << 4);
      size_t kofs = (size_t)kt * 64 + srcc;
      llds16(Ag + (size_t)(m0 + row) * K2 + kofs, (char*)&As[buf][0] + c * 1024);
      llds16(Bg + (size_t)(n0 + row) * K2 + kofs, (char*)&Bs[buf][0] + c * 1024);
    }
  };

  f32x4 acc[4][4] = {};
  const int nk = K >> 5;
  stage(0, 0);
  stage(1, 1);
  int cur = 0;
  for (int t = 0; t < nk; ++t) {
    if (t + 1 < nk) asm volatile("s_waitcnt vmcnt(4)" ::: "memory");
    else            asm volatile("s_waitcnt vmcnt(0)" ::: "memory");
    __builtin_amdgcn_s_barrier();
    MEMBAR();
    if (t + 2 < nk) stage(cur + 2 >= 3 ? cur - 1 : cur + 2, t + 2);

    const unsigned short* Ab = &As[cur][0];
    const unsigned short* Bb = &Bs[cur][0];
    bf16x8 af[4], bfr[4];
#pragma unroll
    for (int m = 0; m < 4; ++m) {
      int row = wr * 64 + m * 16 + l15;
      af[m] = *(const bf16x8*)((const char*)Ab + row * 64 + ((lg * 16) ^ (((row >> 1) & 3) << 4)));
    }
#pragma unroll
    for (int n = 0; n < 4; ++n) {
      int row = wc * 64 + n * 16 + l15;
      bfr[n] = *(const bf16x8*)((const char*)Bb + row * 64 + ((lg * 16) ^ (((row >> 1) & 3) << 4)));
    }
#pragma unroll
    for (int m = 0; m < 4; ++m)
#pragma unroll
      for (int n = 0; n < 4; ++n)
        acc[m][n] = __builtin_amdgcn_mfma_f32_16x16x32_bf16(af[m], bfr[n], acc[m][n], 0, 0, 0);
    cur = (cur == 2) ? 0 : cur + 1;
  }

#pragma unroll
  for (int m = 0; m < 4; ++m)
#pragma unroll
    for (int n = 0; n < 4; ++n) {
      int row = m0 + wr * 64 + m * 16 + lg * 4;
      int col = n0 + wc * 64 + n * 16 + l15;
#pragma unroll
      for (int r = 0; r < 4; ++r) {
        if constexpr (std::is_same<OutT, float>::value)
          C[(size_t)(row + r) * N + col] = acc[m][n][r];
        else
          C[(size_t)(row + r) * N + col] = f2bf(acc[m][n][r]);
      }
    }
}

// ---------------- WIDE-WAVE fused QKV GEMM, dbuf-2 + counted vmcnt -----------------
// BM=256, BN=128, BK=32, 4 waves (2M x 2N), per-wave 128x64 (acc[8][4]).
// DOUBLE-buffered LDS (2 x 24 KB = 48 KB) -> 3 blocks/CU; grid 24x32 = 768 =
// 256 CU x 3 = EXACTLY one resident round (no half-empty second round).
// Counted-vmcnt two-barrier loop (validated in attn R15): per iter
// {stage(t+1, buf^1); vmcnt(6) [0 on final]; s_barrier; compute buf; s_barrier}.
__global__ __launch_bounds__(256, 3) void gemm_qkvW(const unsigned short* __restrict__ A,
                                                    const unsigned short* __restrict__ Bt,
                                                    const float* __restrict__ qw,
                                                    const float* __restrict__ kw,
                                                    const float* __restrict__ cosTT,
                                                    const float* __restrict__ sinTT,
                                                    unsigned short* __restrict__ Qr,
                                                    unsigned short* __restrict__ Kr,
                                                    unsigned short* __restrict__ Vtg) {
  constexpr int K = 1024;
  constexpr int nk = K >> 5;                  // 32 K-tiles of 32
  __shared__ unsigned short smem[24576];      // 48 KB: 2 x (A 16KB + B 8KB)
  char* base = (char*)smem;

  const int tid = threadIdx.x;
  const int w = tid >> 6, lane = tid & 63;
  const int l15 = lane & 15, lg = lane >> 4;
  const int wr = w >> 1, wc = w & 1;

  int bx, by;
  block_map(bx, by);                          // grid dim3(24, 32)
  const int m0 = by * 256, n0 = bx * 128;

  const size_t K2 = (size_t)K * 2;
  const char* Ag = (const char*)A;
  const char* Bg = (const char*)Bt;
  const int rc4 = tid >> 2;                   // row within 64-row chunk
  const int cb = (tid & 3) * 16;              // byte col within 64B row

  auto stage = [&](int buf, int kt) {
    char* ab = base + buf * 24576;
#pragma unroll
    for (int j = 0; j < 4; ++j) {             // A: 256 rows
      int row = j * 64 + rc4;
      int srcc = cb ^ (((row >> 1) & 3) << 4);
      llds16(Ag + (size_t)(m0 + row) * K2 + (size_t)kt * 64 + srcc,
             ab + j * 4096 + tid * 16);
    }
#pragma unroll
    for (int j = 0; j < 2; ++j) {             // B: 128 rows
      int row = j * 64 + rc4;
      int srcc = cb ^ (((row >> 1) & 3) << 4);
      llds16(Bg + (size_t)(n0 + row) * K2 + (size_t)kt * 64 + srcc,
             ab + 16384 + j * 4096 + tid * 16);
    }
  };

  f32x4 acc[8][4] = {};
  stage(0, 0);
  for (int t = 0; t < nk; ++t) {
    const int cur = t & 1;
    if (t + 1 < nk) {
      stage(cur ^ 1, t + 1);                  // issue next tile: my 6 loads
      asm volatile("s_waitcnt vmcnt(6)" ::: "memory");   // wait MY tile-t loads
    } else {
      asm volatile("s_waitcnt vmcnt(0)" ::: "memory");   // final iter: drain
    }
    __builtin_amdgcn_s_barrier();             // all waves' tile-t loads visible
    MEMBAR();

    const char* Ab = base + cur * 24576;
    const char* Bb = Ab + 16384;
    bf16x8 af[8], bfr[4];
#pragma unroll
    for (int m = 0; m < 8; ++m) {
      int row = wr * 128 + m * 16 + l15;
      af[m] = *(const bf16x8*)(Ab + row * 64 + ((lg * 16) ^ (((row >> 1) & 3) << 4)));
    }
#pragma unroll
    for (int n = 0; n < 4; ++n) {
      int row = wc * 64 + n * 16 + l15;
      bfr[n] = *(const bf16x8*)(Bb + row * 64 + ((lg * 16) ^ (((row >> 1) & 3) << 4)));
    }
    __builtin_amdgcn_s_setprio(1);
#pragma unroll
    for (int m = 0; m < 8; ++m)
#pragma unroll
      for (int n = 0; n < 4; ++n)
        acc[m][n] = __builtin_amdgcn_mfma_f32_16x16x32_bf16(af[m], bfr[n], acc[m][n], 0, 0, 0);
    __builtin_amdgcn_s_setprio(0);
    MEMBAR();
    __builtin_amdgcn_s_barrier();             // reads done before next restage (WAR)
    MEMBAR();
  }

  __syncthreads();                            // K-loop done; reuse LDS as bounce

  // ---- fused epilogue (two 64-row chunks) ----
  const int head2 = bx * 2 + wc;              // 0..47
  const int cls = head2 >> 4;                 // 0=Q, 1=K, 2=V
  const int head = head2 & 15;
  const int rowb = m0 + wr * 128;
  const int b = rowb >> 11;
  const int tl = rowb & 2047;
  const int bh = b * 16 + head;
  unsigned short* tb = smem + w * 4864;       // per-wave 9728 B bounce tile (64 x 76)

  if (cls < 2) {
    const float* wt = cls ? kw : qw;
    const float scale = cls ? 1.0f : 0.18033688011112042f;   // log2(e)/8 folded into Q
    unsigned short* outp = cls ? Kr : Qr;
    float wv[4];
#pragma unroll
    for (int n = 0; n < 4; ++n) wv[n] = wt[n * 16 + l15];
    const float* c0p = cosTT + l15 * 2048;
    const float* c1p = cosTT + (16 + l15) * 2048;
    const float* s0p = sinTT + l15 * 2048;
    const float* s1p = sinTT + (16 + l15) * 2048;
#pragma unroll
    for (int chunk = 0; chunk < 2; ++chunk) {
#pragma unroll
      for (int q = 0; q < 4; ++q) {
        const int m = chunk * 4 + q;
        int t0 = tl + m * 16 + lg * 4;
        f32x4 ssq = {};
#pragma unroll
        for (int n = 0; n < 4; ++n) ssq += acc[m][n] * acc[m][n];
#pragma unroll
        for (int r = 0; r < 4; ++r) {
          float v = ssq[r];
          v += __shfl_xor(v, 1); v += __shfl_xor(v, 2);
          v += __shfl_xor(v, 4); v += __shfl_xor(v, 8);
          ssq[r] = rsqrtf(v * (1.0f / 64.0f) + 1e-5f) * scale;
        }
        f32x4 nv[4];
#pragma unroll
        for (int n = 0; n < 4; ++n) nv[n] = acc[m][n] * ssq * wv[n];
        f32x4 cv0 = *(const f32x4*)(c0p + t0);
        f32x4 cv1 = *(const f32x4*)(c1p + t0);
        f32x4 sv0 = *(const f32x4*)(s0p + t0);
        f32x4 sv1 = *(const f32x4*)(s1p + t0);
        f32x4 ov[4];
        ov[0] = nv[0] * cv0 - nv[2] * sv0;
        ov[1] = nv[1] * cv1 - nv[3] * sv1;
        ov[2] = nv[2] * cv0 + nv[0] * sv0;
        ov[3] = nv[3] * cv1 + nv[1] * sv1;
        int tloc = q * 16 + lg * 4;
#pragma unroll
        for (int n = 0; n < 4; ++n)
#pragma unroll
          for (int r = 0; r < 4; ++r)
            tb[(tloc + r) * 76 + n * 16 + l15] = f2bf(ov[n][r]);
      }
      MEMBAR();                               // per-wave LDS in-order
      const int t = lane;
      unsigned short* yp = outp + ((size_t)bh * 2048 + tl + chunk * 64 + t) * 64;
#pragma unroll
      for (int j = 0; j < 8; ++j)
        *(bf16x8*)(yp + j * 8) = *(const bf16x8*)(tb + t * 76 + j * 8);
      MEMBAR();                               // bounce reads before next chunk's writes
    }
  } else {
#pragma unroll
    for (int chunk = 0; chunk < 2; ++chunk) {
#pragma unroll
      for (int q = 0; q < 4; ++q) {
        const int m = chunk * 4 + q;
#pragma unroll
        for (int n = 0; n < 4; ++n) {
          int d = n * 16 + l15, tloc = q * 16 + lg * 4;
          ushort4 pk;
          pk.x = f2bf(acc[m][n][0]); pk.y = f2bf(acc[m][n][1]);
          pk.z = f2bf(acc[m][n][2]); pk.w = f2bf(acc[m][n][3]);
          *(ushort4*)(tb + d * 76 + tloc) = pk;
        }
      }
      MEMBAR();
      int d2 = lane;
      unsigned short* vp = Vtg + ((size_t)bh * 64 + d2) * 2048 + tl + chunk * 64;
#pragma unroll
      for (int j = 0; j < 8; ++j) {
        bf16x8 vv = *(const bf16x8*)(tb + d2 * 76 + j * 8);
        *(bf16x8*)(vp + j * 8) = vv;
      }
      MEMBAR();
    }
  }
}

// ---------------- causal flash attention: QBLK=64, counted-vmcnt no-drain loop -------
// (R15 version, verified)
__global__ __launch_bounds__(256) void attn_fwd(const unsigned short* __restrict__ Q,
                                                const unsigned short* __restrict__ K,
                                                const unsigned short* __restrict__ Vtg,
                                                unsigned short* __restrict__ Y) {
  const int bh = blockIdx.x;        // 0..63
  const int pr = blockIdx.y;        // 0..15
  const int b = bh >> 4, h = bh & 15;
  const int tid = threadIdx.x;
  const int w = tid >> 6, lane = tid & 63;
  const int l15 = lane & 15, lg = lane >> 4;

  __shared__ unsigned short Kl[2][64 * 64];   // swizzled [k][d], 128B rows (16384 B)
  __shared__ unsigned short Vt[2][64 * 64];   // swizzled [d][k], 128B rows (16384 B)
  __shared__ unsigned short Pl[4][16 * 64];   // per-wave P^T [q][k], 128B rows, swz (8192 B)

  const size_t bhT = (size_t)bh * 2048;
  const char* Kg = (const char*)(K + bhT * 64);          // row stride 128B
  const char* Vg = (const char*)(Vtg + bhT * 64);        // row stride 4096B

  auto stage = [&](int buf, int kt) {
#pragma unroll
    for (int i = 0; i < 2; ++i) {
      int c = w * 2 + i;                     // chunk 0..7, wave-uniform
      int pos = c * 1024 + lane * 16;        // linear byte in 8KB tile
      int row = pos >> 7, cb = pos & 127;
      int srcb = cb ^ ((row & 7) << 4);      // inverse-swizzled source
      llds16(Kg + ((size_t)(kt * 64 + row)) * 128 + srcb,
             (char*)&Kl[buf][0] + c * 1024);
      llds16(Vg + (size_t)row * 4096 + (size_t)kt * 128 + srcb,
             (char*)&Vt[buf][0] + c * 1024);
    }
  };

  auto run_qtile = [&](int qtb) {
    const int qbase = qtb * 64;
    const unsigned short* Qp = Q + (bhT + qbase + w * 16 + l15) * 64 + lg * 8;
    bf16x8 aq[2];
    aq[0] = *(const bf16x8*)(Qp);
    aq[1] = *(const bf16x8*)(Qp + 32);

    f32x4 o[4] = {};        // O^T: lane q=l15, rows d = df*16 + lg*4 + r
    float psum = 0.0f;      // per-lane (q = l15) partial sum over its k slice

    char* Pw = (char*)&Pl[w][0];
    const int psw = (l15 & 7) << 4;       // 16B-granular XOR swizzle keyed by q-row

    for (int kt = 0; kt <= qtb; ++kt) {
      const int cur = kt & 1;
      if (kt < qtb) {
        stage(cur ^ 1, kt + 1);           // issue next tile: my 4 loads
        asm volatile("s_waitcnt vmcnt(4)" ::: "memory");   // wait MY tile-t loads
      } else {
        asm volatile("s_waitcnt vmcnt(0)" ::: "memory");   // final iter: drain
      }
      __builtin_amdgcn_s_barrier();       // all waves' tile-t loads now visible
      MEMBAR();
      const char* Kc = (const char*)&Kl[cur][0];
      const char* Vc = (const char*)&Vt[cur][0];

      f32x4 s[4] = {};      // S^T: lane q=l15, rows k = n*16 + lg*4 + r
      __builtin_amdgcn_s_setprio(1);
#pragma unroll
      for (int n = 0; n < 4; ++n) {
        int r = n * 16 + l15, sw = (r & 7) << 4;
#pragma unroll
        for (int ks = 0; ks < 2; ++ks) {
          bf16x8 bk = *(const bf16x8*)(Kc + r * 128 + ((ks * 64 + lg * 16) ^ sw));
          s[n] = __builtin_amdgcn_mfma_f32_16x16x32_bf16(bk, aq[ks], s[n], 0, 0, 0);
        }
      }
      __builtin_amdgcn_s_setprio(0);

      if (kt == qtb) {   // diagonal tile: causal mask (k_local > q_local)
#pragma unroll
        for (int n = 0; n < 4; ++n)
#pragma unroll
          for (int r = 0; r < 4; ++r)
            if (n * 16 + lg * 4 + r > w * 16 + l15) s[n][r] = -1e30f;
      }

      // p = exp2(s); per-lane psum; truncation-pack pairs -> b64 LDS writes
#pragma unroll
      for (int n = 0; n < 4; ++n) {
        float p0 = __builtin_exp2f(s[n][0]);
        float p1 = __builtin_exp2f(s[n][1]);
        float p2 = __builtin_exp2f(s[n][2]);
        float p3 = __builtin_exp2f(s[n][3]);
        psum += (p0 + p1) + (p2 + p3);
        unsigned u0 = __builtin_bit_cast(unsigned, p0);
        unsigned u1 = __builtin_bit_cast(unsigned, p1);
        unsigned u2 = __builtin_bit_cast(unsigned, p2);
        unsigned u3 = __builtin_bit_cast(unsigned, p3);
        uint2 pk;
        pk.x = (u0 >> 16) | (u1 & 0xffff0000u);
        pk.y = (u2 >> 16) | (u3 & 0xffff0000u);
        *(uint2*)(Pw + l15 * 128 + ((n * 32 + lg * 8) ^ psw)) = pk;
      }
      MEMBAR();  // keep P stores before P reads (per-wave LDS in-order)

      bf16x8 ap[2];
      ap[0] = *(const bf16x8*)(Pw + l15 * 128 + ((lg * 16) ^ psw));
      ap[1] = *(const bf16x8*)(Pw + l15 * 128 + ((64 + lg * 16) ^ psw));

      __builtin_amdgcn_s_setprio(1);
#pragma unroll
      for (int df = 0; df < 4; ++df) {
        int rr = df * 16 + l15, sw = (rr & 7) << 4;
#pragma unroll
        for (int ks = 0; ks < 2; ++ks) {
          bf16x8 bv = *(const bf16x8*)(Vc + rr * 128 + ((ks * 64 + lg * 16) ^ sw));
          o[df] = __builtin_amdgcn_mfma_f32_16x16x32_bf16(bv, ap[ks], o[df], 0, 0, 0);
        }
      }
      __builtin_amdgcn_s_setprio(0);
      MEMBAR();
      __builtin_amdgcn_s_barrier();       // all waves done reading before restage
      MEMBAR();
    }

    // full row-sum: combine the 4 lanes sharing this q (lg differs in bits 4..5)
    psum += __shfl_xor(psum, 16);
    psum += __shfl_xor(psum, 32);
    float inv = 1.0f / psum;

    size_t q = qbase + w * 16 + l15;
    unsigned short* yp = Y + ((size_t)b * 2048 + q) * 1024 + h * 64 + lg * 4;
#pragma unroll
    for (int df = 0; df < 4; ++df) {
      ushort4 v;
      v.x = f2bf(o[df][0] * inv);
      v.y = f2bf(o[df][1] * inv);
      v.z = f2bf(o[df][2] * inv);
      v.w = f2bf(o[df][3] * inv);
      *(ushort4*)(yp + df * 16) = v;
    }
  };

  // heavy segment then light segment; every block: 33 kv-tile iterations total
  stage(0, 0);
  run_qtile(31 - pr);
  stage(0, 0);
  run_qtile(pr);
}

// ---------------- launch ----------------
extern "C" void kernel_launch(void* const* d_in, const int* in_sizes, int n_in,
                              void* d_out, int out_size, void* d_ws, size_t ws_size,
                              hipStream_t stream) {
  const float* x = (const float*)d_in[0];
  const float* Wqkv = (const float*)d_in[1];
  const float* Wproj = (const float*)d_in[2];
  const float* qw = (const float*)d_in[3];
  const float* kw = (const float*)d_in[4];
  float* out = (float*)d_out;

  char* ws = (char*)d_ws;
  unsigned short* xb = (unsigned short*)ws;        ws += (size_t)8192 * 1024 * 2;
  unsigned short* wqkvt = (unsigned short*)ws;     ws += (size_t)3072 * 1024 * 2;
  unsigned short* wprojt = (unsigned short*)ws;    ws += (size_t)1024 * 1024 * 2;
  unsigned short* Qr = (unsigned short*)ws;        ws += (size_t)64 * 2048 * 64 * 2;
  unsigned short* Kr = (unsigned short*)ws;        ws += (size_t)64 * 2048 * 64 * 2;
  unsigned short* Vtg = (unsigned short*)ws;       ws += (size_t)64 * 64 * 2048 * 2;
  unsigned short* yb = (unsigned short*)ws;        ws += (size_t)8192 * 1024 * 2;
  float* cosTT = (float*)ws;                       ws += (size_t)32 * 2048 * 4;
  float* sinTT = (float*)ws;                       ws += (size_t)32 * 2048 * 4;

  cvt_f32_bf16<<<2048, 256, 0, stream>>>(x, xb, 8192 * 1024 / 4);
  transpose_f32_bf16<<<dim3(48, 16), 256, 0, stream>>>(Wqkv, wqkvt, 1024, 3072);
  transpose_f32_bf16<<<dim3(16, 16), 256, 0, stream>>>(Wproj, wprojt, 1024, 1024);
  rope_tabT<<<256, 256, 0, stream>>>(cosTT, sinTT);
  gemm_qkvW<<<dim3(24, 32), 256, 0, stream>>>(xb, wqkvt, qw, kw, cosTT, sinTT, Qr, Kr, Vtg);
  attn_fwd<<<dim3(64, 16), 256, 0, stream>>>(Qr, Kr, Vtg, yb);
  gemm_ring<float><<<dim3(8, 64), 256, 0, stream>>>(yb, wprojt, out, 8192, 1024, 1024);
}

// Round 17
// 211.435 us; speedup vs baseline: 1.2447x; 1.2447x over previous
//
#include <hip/hip_runtime.h>
#include <cstdint>
#include <type_traits>

// ---------------- common types / helpers ----------------
typedef __attribute__((ext_vector_type(8))) short bf16x8;   // 8 bf16 in 4 VGPRs
typedef __attribute__((ext_vector_type(4))) float f32x4;

typedef unsigned int __attribute__((address_space(1))) as1_uint;
typedef unsigned int __attribute__((address_space(3))) as3_uint;

__device__ __forceinline__ void llds16(const void* g, void* l) {
  // async global->LDS, 16B per lane; LDS dst is wave-uniform base + lane*16
  __builtin_amdgcn_global_load_lds((const as1_uint*)g, (as3_uint*)l, 16, 0, 0);
}

__device__ __forceinline__ unsigned short f2bf(float f) {
  unsigned int u = __builtin_bit_cast(unsigned int, f);
  u = (u + 0x7fffu + ((u >> 16) & 1u)) >> 16;   // RNE
  return (unsigned short)u;
}
__device__ __forceinline__ float bf2f(unsigned short h) {
  unsigned int u = ((unsigned int)h) << 16;
  return __builtin_bit_cast(float, u);
}

#define MEMBAR() asm volatile("" ::: "memory")

// ---------------- elementwise convert f32 -> bf16 ----------------
__global__ __launch_bounds__(256) void cvt_f32_bf16(const float* __restrict__ in,
                                                    unsigned short* __restrict__ out, int n4) {
  int i = blockIdx.x * blockDim.x + threadIdx.x;
  int stride = gridDim.x * blockDim.x;
  for (; i < n4; i += stride) {
    float4 v = ((const float4*)in)[i];
    uint2 p;
    p.x = (unsigned)f2bf(v.x) | ((unsigned)f2bf(v.y) << 16);
    p.y = (unsigned)f2bf(v.z) | ((unsigned)f2bf(v.w) << 16);
    ((uint2*)out)[i] = p;
  }
}

// ---------------- transpose + convert: W[K][N] f32 -> Wt[N][K] bf16 ----------------
__global__ __launch_bounds__(256) void transpose_f32_bf16(const float* __restrict__ W,
                                                          unsigned short* __restrict__ Wt,
                                                          int K, int N) {
  __shared__ float tile[64][65];
  int n0 = blockIdx.x * 64, k0 = blockIdx.y * 64;
  int t = threadIdx.x;
  int lr = t >> 4, lc = (t & 15) * 4;
#pragma unroll
  for (int i = 0; i < 4; ++i) {
    int k = lr + i * 16;
    float4 v = *(const float4*)&W[(size_t)(k0 + k) * N + n0 + lc];
    tile[k][lc] = v.x; tile[k][lc + 1] = v.y; tile[k][lc + 2] = v.z; tile[k][lc + 3] = v.w;
  }
  __syncthreads();
  int n = t >> 2, kc = (t & 3) * 16;
  unsigned short* dst = &Wt[(size_t)(n0 + n) * K + k0 + kc];
#pragma unroll
  for (int j = 0; j < 16; ++j) dst[j] = f2bf(tile[kc + j][n]);
}

// ---------------- RoPE tables (TRANSPOSED): cos/sin [32][2048] ----------------
__global__ __launch_bounds__(256) void rope_tabT(float* __restrict__ cosT, float* __restrict__ sinT) {
  int i = blockIdx.x * 256 + threadIdx.x;  // < 32*2048
  int dm = i >> 11, t = i & 2047;
  float inv = powf(10000.0f, -(float)dm * (1.0f / 32.0f));
  float a = (float)t * inv;
  cosT[i] = cosf(a);
  sinT[i] = sinf(a);
}

// B-panel-hot XCD block mapping (requires gridDim.y % 8 == 0)
__device__ __forceinline__ void block_map(int& bx, int& by) {
  const int lin = blockIdx.y * gridDim.x + blockIdx.x;
  const int xcd = lin & 7;
  const int idx = lin >> 3;
  const int ych = gridDim.y >> 3;
  by = xcd * ych + (idx & (ych - 1));
  bx = idx / ych;
}

// ---------------- ring-3 NT GEMM (proj): C[M][N] = A[M][K] * Bt[N][K]^T --------------
// vmcnt(4) steady-state; vmcnt(0) on the FINAL iteration.
template <typename OutT>
__global__ __launch_bounds__(256) void gemm_ring(const unsigned short* __restrict__ A,
                                                 const unsigned short* __restrict__ Bt,
                                                 OutT* __restrict__ C, int M, int N, int K) {
  __shared__ unsigned short As[3][128 * 32];
  __shared__ unsigned short Bs[3][128 * 32];
  const int tid = threadIdx.x;
  const int w = tid >> 6, lane = tid & 63;
  const int l15 = lane & 15, lg = lane >> 4;
  const int wr = w >> 1, wc = w & 1;

  int bx, by;
  block_map(bx, by);
  const int m0 = by * 128, n0 = bx * 128;

  const size_t K2 = (size_t)K * 2;
  const char* Ag = (const char*)A;
  const char* Bg = (const char*)Bt;
  const int rc = lane >> 2;            // row within chunk 0..15
  const int cb = (lane & 3) * 16;      // byte col within row

  auto stage = [&](int buf, int kt) {
#pragma unroll
    for (int i = 0; i < 2; ++i) {
      int c = w + i * 4;
      int row = c * 16 + rc;
      int srcc = cb ^ (((row >> 1) & 3) << 4);
      size_t kofs = (size_t)kt * 64 + srcc;
      llds16(Ag + (size_t)(m0 + row) * K2 + kofs, (char*)&As[buf][0] + c * 1024);
      llds16(Bg + (size_t)(n0 + row) * K2 + kofs, (char*)&Bs[buf][0] + c * 1024);
    }
  };

  f32x4 acc[4][4] = {};
  const int nk = K >> 5;
  stage(0, 0);
  stage(1, 1);
  int cur = 0;
  for (int t = 0; t < nk; ++t) {
    if (t + 1 < nk) asm volatile("s_waitcnt vmcnt(4)" ::: "memory");
    else            asm volatile("s_waitcnt vmcnt(0)" ::: "memory");
    __builtin_amdgcn_s_barrier();
    MEMBAR();
    if (t + 2 < nk) stage(cur + 2 >= 3 ? cur - 1 : cur + 2, t + 2);

    const unsigned short* Ab = &As[cur][0];
    const unsigned short* Bb = &Bs[cur][0];
    bf16x8 af[4], bfr[4];
#pragma unroll
    for (int m = 0; m < 4; ++m) {
      int row = wr * 64 + m * 16 + l15;
      af[m] = *(const bf16x8*)((const char*)Ab + row * 64 + ((lg * 16) ^ (((row >> 1) & 3) << 4)));
    }
#pragma unroll
    for (int n = 0; n < 4; ++n) {
      int row = wc * 64 + n * 16 + l15;
      bfr[n] = *(const bf16x8*)((const char*)Bb + row * 64 + ((lg * 16) ^ (((row >> 1) & 3) << 4)));
    }
#pragma unroll
    for (int m = 0; m < 4; ++m)
#pragma unroll
      for (int n = 0; n < 4; ++n)
        acc[m][n] = __builtin_amdgcn_mfma_f32_16x16x32_bf16(af[m], bfr[n], acc[m][n], 0, 0, 0);
    cur = (cur == 2) ? 0 : cur + 1;
  }

#pragma unroll
  for (int m = 0; m < 4; ++m)
#pragma unroll
    for (int n = 0; n < 4; ++n) {
      int row = m0 + wr * 64 + m * 16 + lg * 4;
      int col = n0 + wc * 64 + n * 16 + l15;
#pragma unroll
      for (int r = 0; r < 4; ++r) {
        if constexpr (std::is_same<OutT, float>::value)
          C[(size_t)(row + r) * N + col] = acc[m][n][r];
        else
          C[(size_t)(row + r) * N + col] = f2bf(acc[m][n][r]);
      }
    }
}

// ---------------- WIDE-WAVE fused QKV GEMM, dbuf-2 + counted vmcnt -----------------
// BM=256, BN=128, BK=32, 4 waves (2M x 2N), per-wave 128x64 (acc[8][4]).
// DOUBLE-buffered LDS (2 x 24 KB = 48 KB) -> 3 blocks/CU by LDS; NO min-waves
// launch-bounds hint (R16's (256,3) capped VGPR at 84 < the 128 needed for
// acc[8][4] -> scratch spill, WRITE_SIZE 49->342 MB, 2x slowdown).
// Counted-vmcnt two-barrier loop: per iter {stage(t+1, buf^1); vmcnt(6)
// [0 on final]; s_barrier; compute buf; s_barrier}.
__global__ __launch_bounds__(256) void gemm_qkvW(const unsigned short* __restrict__ A,
                                                 const unsigned short* __restrict__ Bt,
                                                 const float* __restrict__ qw,
                                                 const float* __restrict__ kw,
                                                 const float* __restrict__ cosTT,
                                                 const float* __restrict__ sinTT,
                                                 unsigned short* __restrict__ Qr,
                                                 unsigned short* __restrict__ Kr,
                                                 unsigned short* __restrict__ Vtg) {
  constexpr int K = 1024;
  constexpr int nk = K >> 5;                  // 32 K-tiles of 32
  __shared__ unsigned short smem[24576];      // 48 KB: 2 x (A 16KB + B 8KB)
  char* base = (char*)smem;

  const int tid = threadIdx.x;
  const int w = tid >> 6, lane = tid & 63;
  const int l15 = lane & 15, lg = lane >> 4;
  const int wr = w >> 1, wc = w & 1;

  int bx, by;
  block_map(bx, by);                          // grid dim3(24, 32)
  const int m0 = by * 256, n0 = bx * 128;

  const size_t K2 = (size_t)K * 2;
  const char* Ag = (const char*)A;
  const char* Bg = (const char*)Bt;
  const int rc4 = tid >> 2;                   // row within 64-row chunk
  const int cb = (tid & 3) * 16;              // byte col within 64B row

  auto stage = [&](int buf, int kt) {
    char* ab = base + buf * 24576;
#pragma unroll
    for (int j = 0; j < 4; ++j) {             // A: 256 rows
      int row = j * 64 + rc4;
      int srcc = cb ^ (((row >> 1) & 3) << 4);
      llds16(Ag + (size_t)(m0 + row) * K2 + (size_t)kt * 64 + srcc,
             ab + j * 4096 + tid * 16);
    }
#pragma unroll
    for (int j = 0; j < 2; ++j) {             // B: 128 rows
      int row = j * 64 + rc4;
      int srcc = cb ^ (((row >> 1) & 3) << 4);
      llds16(Bg + (size_t)(n0 + row) * K2 + (size_t)kt * 64 + srcc,
             ab + 16384 + j * 4096 + tid * 16);
    }
  };

  f32x4 acc[8][4] = {};
  stage(0, 0);
  for (int t = 0; t < nk; ++t) {
    const int cur = t & 1;
    if (t + 1 < nk) {
      stage(cur ^ 1, t + 1);                  // issue next tile: my 6 loads
      asm volatile("s_waitcnt vmcnt(6)" ::: "memory");   // wait MY tile-t loads
    } else {
      asm volatile("s_waitcnt vmcnt(0)" ::: "memory");   // final iter: drain
    }
    __builtin_amdgcn_s_barrier();             // all waves' tile-t loads visible
    MEMBAR();

    const char* Ab = base + cur * 24576;
    const char* Bb = Ab + 16384;
    bf16x8 af[8], bfr[4];
#pragma unroll
    for (int m = 0; m < 8; ++m) {
      int row = wr * 128 + m * 16 + l15;
      af[m] = *(const bf16x8*)(Ab + row * 64 + ((lg * 16) ^ (((row >> 1) & 3) << 4)));
    }
#pragma unroll
    for (int n = 0; n < 4; ++n) {
      int row = wc * 64 + n * 16 + l15;
      bfr[n] = *(const bf16x8*)(Bb + row * 64 + ((lg * 16) ^ (((row >> 1) & 3) << 4)));
    }
    __builtin_amdgcn_s_setprio(1);
#pragma unroll
    for (int m = 0; m < 8; ++m)
#pragma unroll
      for (int n = 0; n < 4; ++n)
        acc[m][n] = __builtin_amdgcn_mfma_f32_16x16x32_bf16(af[m], bfr[n], acc[m][n], 0, 0, 0);
    __builtin_amdgcn_s_setprio(0);
    MEMBAR();
    __builtin_amdgcn_s_barrier();             // reads done before next restage (WAR)
    MEMBAR();
  }

  __syncthreads();                            // K-loop done; reuse LDS as bounce

  // ---- fused epilogue (two 64-row chunks) ----
  const int head2 = bx * 2 + wc;              // 0..47
  const int cls = head2 >> 4;                 // 0=Q, 1=K, 2=V
  const int head = head2 & 15;
  const int rowb = m0 + wr * 128;
  const int b = rowb >> 11;
  const int tl = rowb & 2047;
  const int bh = b * 16 + head;
  unsigned short* tb = smem + w * 4864;       // per-wave 9728 B bounce tile (64 x 76)

  if (cls < 2) {
    const float* wt = cls ? kw : qw;
    const float scale = cls ? 1.0f : 0.18033688011112042f;   // log2(e)/8 folded into Q
    unsigned short* outp = cls ? Kr : Qr;
    float wv[4];
#pragma unroll
    for (int n = 0; n < 4; ++n) wv[n] = wt[n * 16 + l15];
    const float* c0p = cosTT + l15 * 2048;
    const float* c1p = cosTT + (16 + l15) * 2048;
    const float* s0p = sinTT + l15 * 2048;
    const float* s1p = sinTT + (16 + l15) * 2048;
#pragma unroll
    for (int chunk = 0; chunk < 2; ++chunk) {
#pragma unroll
      for (int q = 0; q < 4; ++q) {
        const int m = chunk * 4 + q;
        int t0 = tl + m * 16 + lg * 4;
        f32x4 ssq = {};
#pragma unroll
        for (int n = 0; n < 4; ++n) ssq += acc[m][n] * acc[m][n];
#pragma unroll
        for (int r = 0; r < 4; ++r) {
          float v = ssq[r];
          v += __shfl_xor(v, 1); v += __shfl_xor(v, 2);
          v += __shfl_xor(v, 4); v += __shfl_xor(v, 8);
          ssq[r] = rsqrtf(v * (1.0f / 64.0f) + 1e-5f) * scale;
        }
        f32x4 nv[4];
#pragma unroll
        for (int n = 0; n < 4; ++n) nv[n] = acc[m][n] * ssq * wv[n];
        f32x4 cv0 = *(const f32x4*)(c0p + t0);
        f32x4 cv1 = *(const f32x4*)(c1p + t0);
        f32x4 sv0 = *(const f32x4*)(s0p + t0);
        f32x4 sv1 = *(const f32x4*)(s1p + t0);
        f32x4 ov[4];
        ov[0] = nv[0] * cv0 - nv[2] * sv0;
        ov[1] = nv[1] * cv1 - nv[3] * sv1;
        ov[2] = nv[2] * cv0 + nv[0] * sv0;
        ov[3] = nv[3] * cv1 + nv[1] * sv1;
        int tloc = q * 16 + lg * 4;
#pragma unroll
        for (int n = 0; n < 4; ++n)
#pragma unroll
          for (int r = 0; r < 4; ++r)
            tb[(tloc + r) * 76 + n * 16 + l15] = f2bf(ov[n][r]);
      }
      MEMBAR();                               // per-wave LDS in-order
      const int t = lane;
      unsigned short* yp = outp + ((size_t)bh * 2048 + tl + chunk * 64 + t) * 64;
#pragma unroll
      for (int j = 0; j < 8; ++j)
        *(bf16x8*)(yp + j * 8) = *(const bf16x8*)(tb + t * 76 + j * 8);
      MEMBAR();                               // bounce reads before next chunk's writes
    }
  } else {
#pragma unroll
    for (int chunk = 0; chunk < 2; ++chunk) {
#pragma unroll
      for (int q = 0; q < 4; ++q) {
        const int m = chunk * 4 + q;
#pragma unroll
        for (int n = 0; n < 4; ++n) {
          int d = n * 16 + l15, tloc = q * 16 + lg * 4;
          ushort4 pk;
          pk.x = f2bf(acc[m][n][0]); pk.y = f2bf(acc[m][n][1]);
          pk.z = f2bf(acc[m][n][2]); pk.w = f2bf(acc[m][n][3]);
          *(ushort4*)(tb + d * 76 + tloc) = pk;
        }
      }
      MEMBAR();
      int d2 = lane;
      unsigned short* vp = Vtg + ((size_t)bh * 64 + d2) * 2048 + tl + chunk * 64;
#pragma unroll
      for (int j = 0; j < 8; ++j) {
        bf16x8 vv = *(const bf16x8*)(tb + d2 * 76 + j * 8);
        *(bf16x8*)(vp + j * 8) = vv;
      }
      MEMBAR();
    }
  }
}

// ---------------- causal flash attention: QBLK=64, counted-vmcnt no-drain loop -------
// (R15 version, verified)
__global__ __launch_bounds__(256) void attn_fwd(const unsigned short* __restrict__ Q,
                                                const unsigned short* __restrict__ K,
                                                const unsigned short* __restrict__ Vtg,
                                                unsigned short* __restrict__ Y) {
  const int bh = blockIdx.x;        // 0..63
  const int pr = blockIdx.y;        // 0..15
  const int b = bh >> 4, h = bh & 15;
  const int tid = threadIdx.x;
  const int w = tid >> 6, lane = tid & 63;
  const int l15 = lane & 15, lg = lane >> 4;

  __shared__ unsigned short Kl[2][64 * 64];   // swizzled [k][d], 128B rows (16384 B)
  __shared__ unsigned short Vt[2][64 * 64];   // swizzled [d][k], 128B rows (16384 B)
  __shared__ unsigned short Pl[4][16 * 64];   // per-wave P^T [q][k], 128B rows, swz (8192 B)

  const size_t bhT = (size_t)bh * 2048;
  const char* Kg = (const char*)(K + bhT * 64);          // row stride 128B
  const char* Vg = (const char*)(Vtg + bhT * 64);        // row stride 4096B

  auto stage = [&](int buf, int kt) {
#pragma unroll
    for (int i = 0; i < 2; ++i) {
      int c = w * 2 + i;                     // chunk 0..7, wave-uniform
      int pos = c * 1024 + lane * 16;        // linear byte in 8KB tile
      int row = pos >> 7, cb = pos & 127;
      int srcb = cb ^ ((row & 7) << 4);      // inverse-swizzled source
      llds16(Kg + ((size_t)(kt * 64 + row)) * 128 + srcb,
             (char*)&Kl[buf][0] + c * 1024);
      llds16(Vg + (size_t)row * 4096 + (size_t)kt * 128 + srcb,
             (char*)&Vt[buf][0] + c * 1024);
    }
  };

  auto run_qtile = [&](int qtb) {
    const int qbase = qtb * 64;
    const unsigned short* Qp = Q + (bhT + qbase + w * 16 + l15) * 64 + lg * 8;
    bf16x8 aq[2];
    aq[0] = *(const bf16x8*)(Qp);
    aq[1] = *(const bf16x8*)(Qp + 32);

    f32x4 o[4] = {};        // O^T: lane q=l15, rows d = df*16 + lg*4 + r
    float psum = 0.0f;      // per-lane (q = l15) partial sum over its k slice

    char* Pw = (char*)&Pl[w][0];
    const int psw = (l15 & 7) << 4;       // 16B-granular XOR swizzle keyed by q-row

    for (int kt = 0; kt <= qtb; ++kt) {
      const int cur = kt & 1;
      if (kt < qtb) {
        stage(cur ^ 1, kt + 1);           // issue next tile: my 4 loads
        asm volatile("s_waitcnt vmcnt(4)" ::: "memory");   // wait MY tile-t loads
      } else {
        asm volatile("s_waitcnt vmcnt(0)" ::: "memory");   // final iter: drain
      }
      __builtin_amdgcn_s_barrier();       // all waves' tile-t loads now visible
      MEMBAR();
      const char* Kc = (const char*)&Kl[cur][0];
      const char* Vc = (const char*)&Vt[cur][0];

      f32x4 s[4] = {};      // S^T: lane q=l15, rows k = n*16 + lg*4 + r
      __builtin_amdgcn_s_setprio(1);
#pragma unroll
      for (int n = 0; n < 4; ++n) {
        int r = n * 16 + l15, sw = (r & 7) << 4;
#pragma unroll
        for (int ks = 0; ks < 2; ++ks) {
          bf16x8 bk = *(const bf16x8*)(Kc + r * 128 + ((ks * 64 + lg * 16) ^ sw));
          s[n] = __builtin_amdgcn_mfma_f32_16x16x32_bf16(bk, aq[ks], s[n], 0, 0, 0);
        }
      }
      __builtin_amdgcn_s_setprio(0);

      if (kt == qtb) {   // diagonal tile: causal mask (k_local > q_local)
#pragma unroll
        for (int n = 0; n < 4; ++n)
#pragma unroll
          for (int r = 0; r < 4; ++r)
            if (n * 16 + lg * 4 + r > w * 16 + l15) s[n][r] = -1e30f;
      }

      // p = exp2(s); per-lane psum; truncation-pack pairs -> b64 LDS writes
#pragma unroll
      for (int n = 0; n < 4; ++n) {
        float p0 = __builtin_exp2f(s[n][0]);
        float p1 = __builtin_exp2f(s[n][1]);
        float p2 = __builtin_exp2f(s[n][2]);
        float p3 = __builtin_exp2f(s[n][3]);
        psum += (p0 + p1) + (p2 + p3);
        unsigned u0 = __builtin_bit_cast(unsigned, p0);
        unsigned u1 = __builtin_bit_cast(unsigned, p1);
        unsigned u2 = __builtin_bit_cast(unsigned, p2);
        unsigned u3 = __builtin_bit_cast(unsigned, p3);
        uint2 pk;
        pk.x = (u0 >> 16) | (u1 & 0xffff0000u);
        pk.y = (u2 >> 16) | (u3 & 0xffff0000u);
        *(uint2*)(Pw + l15 * 128 + ((n * 32 + lg * 8) ^ psw)) = pk;
      }
      MEMBAR();  // keep P stores before P reads (per-wave LDS in-order)

      bf16x8 ap[2];
      ap[0] = *(const bf16x8*)(Pw + l15 * 128 + ((lg * 16) ^ psw));
      ap[1] = *(const bf16x8*)(Pw + l15 * 128 + ((64 + lg * 16) ^ psw));

      __builtin_amdgcn_s_setprio(1);
#pragma unroll
      for (int df = 0; df < 4; ++df) {
        int rr = df * 16 + l15, sw = (rr & 7) << 4;
#pragma unroll
        for (int ks = 0; ks < 2; ++ks) {
          bf16x8 bv = *(const bf16x8*)(Vc + rr * 128 + ((ks * 64 + lg * 16) ^ sw));
          o[df] = __builtin_amdgcn_mfma_f32_16x16x32_bf16(bv, ap[ks], o[df], 0, 0, 0);
        }
      }
      __builtin_amdgcn_s_setprio(0);
      MEMBAR();
      __builtin_amdgcn_s_barrier();       // all waves done reading before restage
      MEMBAR();
    }

    // full row-sum: combine the 4 lanes sharing this q (lg differs in bits 4..5)
    psum += __shfl_xor(psum, 16);
    psum += __shfl_xor(psum, 32);
    float inv = 1.0f / psum;

    size_t q = qbase + w * 16 + l15;
    unsigned short* yp = Y + ((size_t)b * 2048 + q) * 1024 + h * 64 + lg * 4;
#pragma unroll
    for (int df = 0; df < 4; ++df) {
      ushort4 v;
      v.x = f2bf(o[df][0] * inv);
      v.y = f2bf(o[df][1] * inv);
      v.z = f2bf(o[df][2] * inv);
      v.w = f2bf(o[df][3] * inv);
      *(ushort4*)(yp + df * 16) = v;
    }
  };

  // heavy segment then light segment; every block: 33 kv-tile iterations total
  stage(0, 0);
  run_qtile(31 - pr);
  stage(0, 0);
  run_qtile(pr);
}

// ---------------- launch ----------------
extern "C" void kernel_launch(void* const* d_in, const int* in_sizes, int n_in,
                              void* d_out, int out_size, void* d_ws, size_t ws_size,
                              hipStream_t stream) {
  const float* x = (const float*)d_in[0];
  const float* Wqkv = (const float*)d_in[1];
  const float* Wproj = (const float*)d_in[2];
  const float* qw = (const float*)d_in[3];
  const float* kw = (const float*)d_in[4];
  float* out = (float*)d_out;

  char* ws = (char*)d_ws;
  unsigned short* xb = (unsigned short*)ws;        ws += (size_t)8192 * 1024 * 2;
  unsigned short* wqkvt = (unsigned short*)ws;     ws += (size_t)3072 * 1024 * 2;
  unsigned short* wprojt = (unsigned short*)ws;    ws += (size_t)1024 * 1024 * 2;
  unsigned short* Qr = (unsigned short*)ws;        ws += (size_t)64 * 2048 * 64 * 2;
  unsigned short* Kr = (unsigned short*)ws;        ws += (size_t)64 * 2048 * 64 * 2;
  unsigned short* Vtg = (unsigned short*)ws;       ws += (size_t)64 * 64 * 2048 * 2;
  unsigned short* yb = (unsigned short*)ws;        ws += (size_t)8192 * 1024 * 2;
  float* cosTT = (float*)ws;                       ws += (size_t)32 * 2048 * 4;
  float* sinTT = (float*)ws;                       ws += (size_t)32 * 2048 * 4;

  cvt_f32_bf16<<<2048, 256, 0, stream>>>(x, xb, 8192 * 1024 / 4);
  transpose_f32_bf16<<<dim3(48, 16), 256, 0, stream>>>(Wqkv, wqkvt, 1024, 3072);
  transpose_f32_bf16<<<dim3(16, 16), 256, 0, stream>>>(Wproj, wprojt, 1024, 1024);
  rope_tabT<<<256, 256, 0, stream>>>(cosTT, sinTT);
  gemm_qkvW<<<dim3(24, 32), 256, 0, stream>>>(xb, wqkvt, qw, kw, cosTT, sinTT, Qr, Kr, Vtg);
  attn_fwd<<<dim3(64, 16), 256, 0, stream>>>(Qr, Kr, Vtg, yb);
  gemm_ring<float><<<dim3(8, 64), 256, 0, stream>>>(yb, wprojt, out, 8192, 1024, 1024);
}

// Round 18
// 185.887 us; speedup vs baseline: 1.4158x; 1.1374x over previous
//
#include <hip/hip_runtime.h>
#include <cstdint>
#include <type_traits>

// ---------------- common types / helpers ----------------
typedef __attribute__((ext_vector_type(8))) short bf16x8;   // 8 bf16 in 4 VGPRs
typedef __attribute__((ext_vector_type(4))) float f32x4;

typedef unsigned int __attribute__((address_space(1))) as1_uint;
typedef unsigned int __attribute__((address_space(3))) as3_uint;

__device__ __forceinline__ void llds16(const void* g, void* l) {
  // async global->LDS, 16B per lane; LDS dst is wave-uniform base + lane*16
  __builtin_amdgcn_global_load_lds((const as1_uint*)g, (as3_uint*)l, 16, 0, 0);
}

__device__ __forceinline__ unsigned short f2bf(float f) {
  unsigned int u = __builtin_bit_cast(unsigned int, f);
  u = (u + 0x7fffu + ((u >> 16) & 1u)) >> 16;   // RNE
  return (unsigned short)u;
}
__device__ __forceinline__ float bf2f(unsigned short h) {
  unsigned int u = ((unsigned int)h) << 16;
  return __builtin_bit_cast(float, u);
}

#define MEMBAR() asm volatile("" ::: "memory")

// ---------------- elementwise convert f32 -> bf16 ----------------
__global__ __launch_bounds__(256) void cvt_f32_bf16(const float* __restrict__ in,
                                                    unsigned short* __restrict__ out, int n4) {
  int i = blockIdx.x * blockDim.x + threadIdx.x;
  int stride = gridDim.x * blockDim.x;
  for (; i < n4; i += stride) {
    float4 v = ((const float4*)in)[i];
    uint2 p;
    p.x = (unsigned)f2bf(v.x) | ((unsigned)f2bf(v.y) << 16);
    p.y = (unsigned)f2bf(v.z) | ((unsigned)f2bf(v.w) << 16);
    ((uint2*)out)[i] = p;
  }
}

// ---------------- transpose + convert: W[K][N] f32 -> Wt[N][K] bf16 ----------------
__global__ __launch_bounds__(256) void transpose_f32_bf16(const float* __restrict__ W,
                                                          unsigned short* __restrict__ Wt,
                                                          int K, int N) {
  __shared__ float tile[64][65];
  int n0 = blockIdx.x * 64, k0 = blockIdx.y * 64;
  int t = threadIdx.x;
  int lr = t >> 4, lc = (t & 15) * 4;
#pragma unroll
  for (int i = 0; i < 4; ++i) {
    int k = lr + i * 16;
    float4 v = *(const float4*)&W[(size_t)(k0 + k) * N + n0 + lc];
    tile[k][lc] = v.x; tile[k][lc + 1] = v.y; tile[k][lc + 2] = v.z; tile[k][lc + 3] = v.w;
  }
  __syncthreads();
  int n = t >> 2, kc = (t & 3) * 16;
  unsigned short* dst = &Wt[(size_t)(n0 + n) * K + k0 + kc];
#pragma unroll
  for (int j = 0; j < 16; ++j) dst[j] = f2bf(tile[kc + j][n]);
}

// ---------------- RoPE tables (TRANSPOSED): cos/sin [32][2048] ----------------
__global__ __launch_bounds__(256) void rope_tabT(float* __restrict__ cosT, float* __restrict__ sinT) {
  int i = blockIdx.x * 256 + threadIdx.x;  // < 32*2048
  int dm = i >> 11, t = i & 2047;
  float inv = powf(10000.0f, -(float)dm * (1.0f / 32.0f));
  float a = (float)t * inv;
  cosT[i] = cosf(a);
  sinT[i] = sinf(a);
}

// B-panel-hot XCD block mapping (requires gridDim.y % 8 == 0)
__device__ __forceinline__ void block_map(int& bx, int& by) {
  const int lin = blockIdx.y * gridDim.x + blockIdx.x;
  const int xcd = lin & 7;
  const int idx = lin >> 3;
  const int ych = gridDim.y >> 3;
  by = xcd * ych + (idx & (ych - 1));
  bx = idx / ych;
}

// ---------------- ring-3 NT GEMM (proj): C[M][N] = A[M][K] * Bt[N][K]^T --------------
// vmcnt(4) steady-state; vmcnt(0) on the FINAL iteration.
template <typename OutT>
__global__ __launch_bounds__(256) void gemm_ring(const unsigned short* __restrict__ A,
                                                 const unsigned short* __restrict__ Bt,
                                                 OutT* __restrict__ C, int M, int N, int K) {
  __shared__ unsigned short As[3][128 * 32];
  __shared__ unsigned short Bs[3][128 * 32];
  const int tid = threadIdx.x;
  const int w = tid >> 6, lane = tid & 63;
  const int l15 = lane & 15, lg = lane >> 4;
  const int wr = w >> 1, wc = w & 1;

  int bx, by;
  block_map(bx, by);
  const int m0 = by * 128, n0 = bx * 128;

  const size_t K2 = (size_t)K * 2;
  const char* Ag = (const char*)A;
  const char* Bg = (const char*)Bt;
  const int rc = lane >> 2;            // row within chunk 0..15
  const int cb = (lane & 3) * 16;      // byte col within row

  auto stage = [&](int buf, int kt) {
#pragma unroll
    for (int i = 0; i < 2; ++i) {
      int c = w + i * 4;
      int row = c * 16 + rc;
      int srcc = cb ^ (((row >> 1) & 3) << 4);
      size_t kofs = (size_t)kt * 64 + srcc;
      llds16(Ag + (size_t)(m0 + row) * K2 + kofs, (char*)&As[buf][0] + c * 1024);
      llds16(Bg + (size_t)(n0 + row) * K2 + kofs, (char*)&Bs[buf][0] + c * 1024);
    }
  };

  f32x4 acc[4][4] = {};
  const int nk = K >> 5;
  stage(0, 0);
  stage(1, 1);
  int cur = 0;
  for (int t = 0; t < nk; ++t) {
    if (t + 1 < nk) asm volatile("s_waitcnt vmcnt(4)" ::: "memory");
    else            asm volatile("s_waitcnt vmcnt(0)" ::: "memory");
    __builtin_amdgcn_s_barrier();
    MEMBAR();
    if (t + 2 < nk) stage(cur + 2 >= 3 ? cur - 1 : cur + 2, t + 2);

    const unsigned short* Ab = &As[cur][0];
    const unsigned short* Bb = &Bs[cur][0];
    bf16x8 af[4], bfr[4];
#pragma unroll
    for (int m = 0; m < 4; ++m) {
      int row = wr * 64 + m * 16 + l15;
      af[m] = *(const bf16x8*)((const char*)Ab + row * 64 + ((lg * 16) ^ (((row >> 1) & 3) << 4)));
    }
#pragma unroll
    for (int n = 0; n < 4; ++n) {
      int row = wc * 64 + n * 16 + l15;
      bfr[n] = *(const bf16x8*)((const char*)Bb + row * 64 + ((lg * 16) ^ (((row >> 1) & 3) << 4)));
    }
#pragma unroll
    for (int m = 0; m < 4; ++m)
#pragma unroll
      for (int n = 0; n < 4; ++n)
        acc[m][n] = __builtin_amdgcn_mfma_f32_16x16x32_bf16(af[m], bfr[n], acc[m][n], 0, 0, 0);
    cur = (cur == 2) ? 0 : cur + 1;
  }

#pragma unroll
  for (int m = 0; m < 4; ++m)
#pragma unroll
    for (int n = 0; n < 4; ++n) {
      int row = m0 + wr * 64 + m * 16 + lg * 4;
      int col = n0 + wc * 64 + n * 16 + l15;
#pragma unroll
      for (int r = 0; r < 4; ++r) {
        if constexpr (std::is_same<OutT, float>::value)
          C[(size_t)(row + r) * N + col] = acc[m][n][r];
        else
          C[(size_t)(row + r) * N + col] = f2bf(acc[m][n][r]);
      }
    }
}

// ---------------- WIDE-WAVE fused QKV GEMM (ring-3, distance-2; R13/R15, 90 us) ----
__global__ __launch_bounds__(256, 2) void gemm_qkvW(const unsigned short* __restrict__ A,
                                                    const unsigned short* __restrict__ Bt,
                                                    const float* __restrict__ qw,
                                                    const float* __restrict__ kw,
                                                    const float* __restrict__ cosTT,
                                                    const float* __restrict__ sinTT,
                                                    unsigned short* __restrict__ Qr,
                                                    unsigned short* __restrict__ Kr,
                                                    unsigned short* __restrict__ Vtg) {
  constexpr int K = 1024;
  constexpr int nk = K >> 5;                  // 32 K-tiles of 32
  __shared__ unsigned short smem[36864];      // 72 KB: 3 x (A 16KB + B 8KB)
  char* base = (char*)smem;

  const int tid = threadIdx.x;
  const int w = tid >> 6, lane = tid & 63;
  const int l15 = lane & 15, lg = lane >> 4;
  const int wr = w >> 1, wc = w & 1;

  int bx, by;
  block_map(bx, by);                          // grid dim3(24, 32)
  const int m0 = by * 256, n0 = bx * 128;

  const size_t K2 = (size_t)K * 2;
  const char* Ag = (const char*)A;
  const char* Bg = (const char*)Bt;
  const int rc4 = tid >> 2;                   // row within 64-row chunk
  const int cb = (tid & 3) * 16;              // byte col within 64B row

  auto stage = [&](int buf, int kt) {
    char* ab = base + buf * 24576;
#pragma unroll
    for (int j = 0; j < 4; ++j) {             // A: 256 rows
      int row = j * 64 + rc4;
      int srcc = cb ^ (((row >> 1) & 3) << 4);
      llds16(Ag + (size_t)(m0 + row) * K2 + (size_t)kt * 64 + srcc,
             ab + j * 4096 + tid * 16);
    }
#pragma unroll
    for (int j = 0; j < 2; ++j) {             // B: 128 rows
      int row = j * 64 + rc4;
      int srcc = cb ^ (((row >> 1) & 3) << 4);
      llds16(Bg + (size_t)(n0 + row) * K2 + (size_t)kt * 64 + srcc,
             ab + 16384 + j * 4096 + tid * 16);
    }
  };

  f32x4 acc[8][4] = {};
  stage(0, 0);
  stage(1, 1);
  int cur = 0;
  for (int t = 0; t < nk; ++t) {
    if (t + 1 < nk) asm volatile("s_waitcnt vmcnt(6)" ::: "memory");
    else            asm volatile("s_waitcnt vmcnt(0)" ::: "memory");
    __builtin_amdgcn_s_barrier();
    MEMBAR();
    if (t + 2 < nk) stage(cur + 2 >= 3 ? cur - 1 : cur + 2, t + 2);

    const char* Ab = base + cur * 24576;
    const char* Bb = Ab + 16384;
    bf16x8 af[8], bfr[4];
#pragma unroll
    for (int m = 0; m < 8; ++m) {
      int row = wr * 128 + m * 16 + l15;
      af[m] = *(const bf16x8*)(Ab + row * 64 + ((lg * 16) ^ (((row >> 1) & 3) << 4)));
    }
#pragma unroll
    for (int n = 0; n < 4; ++n) {
      int row = wc * 64 + n * 16 + l15;
      bfr[n] = *(const bf16x8*)(Bb + row * 64 + ((lg * 16) ^ (((row >> 1) & 3) << 4)));
    }
    __builtin_amdgcn_s_setprio(1);
#pragma unroll
    for (int m = 0; m < 8; ++m)
#pragma unroll
      for (int n = 0; n < 4; ++n)
        acc[m][n] = __builtin_amdgcn_mfma_f32_16x16x32_bf16(af[m], bfr[n], acc[m][n], 0, 0, 0);
    __builtin_amdgcn_s_setprio(0);
    cur = (cur == 2) ? 0 : cur + 1;
  }

  __syncthreads();                            // K-loop LDS traffic done; reuse as bounce

  // ---- fused epilogue (two 64-row chunks) ----
  const int head2 = bx * 2 + wc;              // 0..47
  const int cls = head2 >> 4;                 // 0=Q, 1=K, 2=V
  const int head = head2 & 15;
  const int rowb = m0 + wr * 128;
  const int b = rowb >> 11;
  const int tl = rowb & 2047;
  const int bh = b * 16 + head;
  unsigned short* tb = smem + w * 4864;       // per-wave 9728 B bounce tile (64 x 76)

  if (cls < 2) {
    const float* wt = cls ? kw : qw;
    const float scale = cls ? 1.0f : 0.18033688011112042f;   // log2(e)/8 folded into Q
    unsigned short* outp = cls ? Kr : Qr;
    float wv[4];
#pragma unroll
    for (int n = 0; n < 4; ++n) wv[n] = wt[n * 16 + l15];
    const float* c0p = cosTT + l15 * 2048;
    const float* c1p = cosTT + (16 + l15) * 2048;
    const float* s0p = sinTT + l15 * 2048;
    const float* s1p = sinTT + (16 + l15) * 2048;
#pragma unroll
    for (int chunk = 0; chunk < 2; ++chunk) {
#pragma unroll
      for (int q = 0; q < 4; ++q) {
        const int m = chunk * 4 + q;
        int t0 = tl + m * 16 + lg * 4;
        f32x4 ssq = {};
#pragma unroll
        for (int n = 0; n < 4; ++n) ssq += acc[m][n] * acc[m][n];
#pragma unroll
        for (int r = 0; r < 4; ++r) {
          float v = ssq[r];
          v += __shfl_xor(v, 1); v += __shfl_xor(v, 2);
          v += __shfl_xor(v, 4); v += __shfl_xor(v, 8);
          ssq[r] = rsqrtf(v * (1.0f / 64.0f) + 1e-5f) * scale;
        }
        f32x4 nv[4];
#pragma unroll
        for (int n = 0; n < 4; ++n) nv[n] = acc[m][n] * ssq * wv[n];
        f32x4 cv0 = *(const f32x4*)(c0p + t0);
        f32x4 cv1 = *(const f32x4*)(c1p + t0);
        f32x4 sv0 = *(const f32x4*)(s0p + t0);
        f32x4 sv1 = *(const f32x4*)(s1p + t0);
        f32x4 ov[4];
        ov[0] = nv[0] * cv0 - nv[2] * sv0;
        ov[1] = nv[1] * cv1 - nv[3] * sv1;
        ov[2] = nv[2] * cv0 + nv[0] * sv0;
        ov[3] = nv[3] * cv1 + nv[1] * sv1;
        int tloc = q * 16 + lg * 4;
#pragma unroll
        for (int n = 0; n < 4; ++n)
#pragma unroll
          for (int r = 0; r < 4; ++r)
            tb[(tloc + r) * 76 + n * 16 + l15] = f2bf(ov[n][r]);
      }
      MEMBAR();                               // per-wave LDS in-order
      const int t = lane;
      unsigned short* yp = outp + ((size_t)bh * 2048 + tl + chunk * 64 + t) * 64;
#pragma unroll
      for (int j = 0; j < 8; ++j)
        *(bf16x8*)(yp + j * 8) = *(const bf16x8*)(tb + t * 76 + j * 8);
      MEMBAR();                               // bounce reads before next chunk's writes
    }
  } else {
#pragma unroll
    for (int chunk = 0; chunk < 2; ++chunk) {
#pragma unroll
      for (int q = 0; q < 4; ++q) {
        const int m = chunk * 4 + q;
#pragma unroll
        for (int n = 0; n < 4; ++n) {
          int d = n * 16 + l15, tloc = q * 16 + lg * 4;
          ushort4 pk;
          pk.x = f2bf(acc[m][n][0]); pk.y = f2bf(acc[m][n][1]);
          pk.z = f2bf(acc[m][n][2]); pk.w = f2bf(acc[m][n][3]);
          *(ushort4*)(tb + d * 76 + tloc) = pk;
        }
      }
      MEMBAR();
      int d2 = lane;
      unsigned short* vp = Vtg + ((size_t)bh * 64 + d2) * 2048 + tl + chunk * 64;
#pragma unroll
      for (int j = 0; j < 8; ++j) {
        bf16x8 vv = *(const bf16x8*)(tb + d2 * 76 + j * 8);
        *(bf16x8*)(vp + j * 8) = vv;
      }
      MEMBAR();
    }
  }
}

// ---------------- causal flash attention: QBLK=64, counted-vmcnt no-drain loop -------
// (R15 version, verified, best measured)
__global__ __launch_bounds__(256) void attn_fwd(const unsigned short* __restrict__ Q,
                                                const unsigned short* __restrict__ K,
                                                const unsigned short* __restrict__ Vtg,
                                                unsigned short* __restrict__ Y) {
  const int bh = blockIdx.x;        // 0..63
  const int pr = blockIdx.y;        // 0..15
  const int b = bh >> 4, h = bh & 15;
  const int tid = threadIdx.x;
  const int w = tid >> 6, lane = tid & 63;
  const int l15 = lane & 15, lg = lane >> 4;

  __shared__ unsigned short Kl[2][64 * 64];   // swizzled [k][d], 128B rows (16384 B)
  __shared__ unsigned short Vt[2][64 * 64];   // swizzled [d][k], 128B rows (16384 B)
  __shared__ unsigned short Pl[4][16 * 64];   // per-wave P^T [q][k], 128B rows, swz (8192 B)

  const size_t bhT = (size_t)bh * 2048;
  const char* Kg = (const char*)(K + bhT * 64);          // row stride 128B
  const char* Vg = (const char*)(Vtg + bhT * 64);        // row stride 4096B

  auto stage = [&](int buf, int kt) {
#pragma unroll
    for (int i = 0; i < 2; ++i) {
      int c = w * 2 + i;                     // chunk 0..7, wave-uniform
      int pos = c * 1024 + lane * 16;        // linear byte in 8KB tile
      int row = pos >> 7, cb = pos & 127;
      int srcb = cb ^ ((row & 7) << 4);      // inverse-swizzled source
      llds16(Kg + ((size_t)(kt * 64 + row)) * 128 + srcb,
             (char*)&Kl[buf][0] + c * 1024);
      llds16(Vg + (size_t)row * 4096 + (size_t)kt * 128 + srcb,
             (char*)&Vt[buf][0] + c * 1024);
    }
  };

  auto run_qtile = [&](int qtb) {
    const int qbase = qtb * 64;
    const unsigned short* Qp = Q + (bhT + qbase + w * 16 + l15) * 64 + lg * 8;
    bf16x8 aq[2];
    aq[0] = *(const bf16x8*)(Qp);
    aq[1] = *(const bf16x8*)(Qp + 32);

    f32x4 o[4] = {};        // O^T: lane q=l15, rows d = df*16 + lg*4 + r
    float psum = 0.0f;      // per-lane (q = l15) partial sum over its k slice

    char* Pw = (char*)&Pl[w][0];
    const int psw = (l15 & 7) << 4;       // 16B-granular XOR swizzle keyed by q-row

    for (int kt = 0; kt <= qtb; ++kt) {
      const int cur = kt & 1;
      if (kt < qtb) {
        stage(cur ^ 1, kt + 1);           // issue next tile: my 4 loads
        asm volatile("s_waitcnt vmcnt(4)" ::: "memory");   // wait MY tile-t loads
      } else {
        asm volatile("s_waitcnt vmcnt(0)" ::: "memory");   // final iter: drain
      }
      __builtin_amdgcn_s_barrier();       // all waves' tile-t loads now visible
      MEMBAR();
      const char* Kc = (const char*)&Kl[cur][0];
      const char* Vc = (const char*)&Vt[cur][0];

      f32x4 s[4] = {};      // S^T: lane q=l15, rows k = n*16 + lg*4 + r
      __builtin_amdgcn_s_setprio(1);
#pragma unroll
      for (int n = 0; n < 4; ++n) {
        int r = n * 16 + l15, sw = (r & 7) << 4;
#pragma unroll
        for (int ks = 0; ks < 2; ++ks) {
          bf16x8 bk = *(const bf16x8*)(Kc + r * 128 + ((ks * 64 + lg * 16) ^ sw));
          s[n] = __builtin_amdgcn_mfma_f32_16x16x32_bf16(bk, aq[ks], s[n], 0, 0, 0);
        }
      }
      __builtin_amdgcn_s_setprio(0);

      if (kt == qtb) {   // diagonal tile: causal mask (k_local > q_local)
#pragma unroll
        for (int n = 0; n < 4; ++n)
#pragma unroll
          for (int r = 0; r < 4; ++r)
            if (n * 16 + lg * 4 + r > w * 16 + l15) s[n][r] = -1e30f;
      }

      // p = exp2(s); per-lane psum; truncation-pack pairs -> b64 LDS writes
#pragma unroll
      for (int n = 0; n < 4; ++n) {
        float p0 = __builtin_exp2f(s[n][0]);
        float p1 = __builtin_exp2f(s[n][1]);
        float p2 = __builtin_exp2f(s[n][2]);
        float p3 = __builtin_exp2f(s[n][3]);
        psum += (p0 + p1) + (p2 + p3);
        unsigned u0 = __builtin_bit_cast(unsigned, p0);
        unsigned u1 = __builtin_bit_cast(unsigned, p1);
        unsigned u2 = __builtin_bit_cast(unsigned, p2);
        unsigned u3 = __builtin_bit_cast(unsigned, p3);
        uint2 pk;
        pk.x = (u0 >> 16) | (u1 & 0xffff0000u);
        pk.y = (u2 >> 16) | (u3 & 0xffff0000u);
        *(uint2*)(Pw + l15 * 128 + ((n * 32 + lg * 8) ^ psw)) = pk;
      }
      MEMBAR();  // keep P stores before P reads (per-wave LDS in-order)

      bf16x8 ap[2];
      ap[0] = *(const bf16x8*)(Pw + l15 * 128 + ((lg * 16) ^ psw));
      ap[1] = *(const bf16x8*)(Pw + l15 * 128 + ((64 + lg * 16) ^ psw));

      __builtin_amdgcn_s_setprio(1);
#pragma unroll
      for (int df = 0; df < 4; ++df) {
        int rr = df * 16 + l15, sw = (rr & 7) << 4;
#pragma unroll
        for (int ks = 0; ks < 2; ++ks) {
          bf16x8 bv = *(const bf16x8*)(Vc + rr * 128 + ((ks * 64 + lg * 16) ^ sw));
          o[df] = __builtin_amdgcn_mfma_f32_16x16x32_bf16(bv, ap[ks], o[df], 0, 0, 0);
        }
      }
      __builtin_amdgcn_s_setprio(0);
      MEMBAR();
      __builtin_amdgcn_s_barrier();       // all waves done reading before restage
      MEMBAR();
    }

    // full row-sum: combine the 4 lanes sharing this q (lg differs in bits 4..5)
    psum += __shfl_xor(psum, 16);
    psum += __shfl_xor(psum, 32);
    float inv = 1.0f / psum;

    size_t q = qbase + w * 16 + l15;
    unsigned short* yp = Y + ((size_t)b * 2048 + q) * 1024 + h * 64 + lg * 4;
#pragma unroll
    for (int df = 0; df < 4; ++df) {
      ushort4 v;
      v.x = f2bf(o[df][0] * inv);
      v.y = f2bf(o[df][1] * inv);
      v.z = f2bf(o[df][2] * inv);
      v.w = f2bf(o[df][3] * inv);
      *(ushort4*)(yp + df * 16) = v;
    }
  };

  // heavy segment then light segment; every block: 33 kv-tile iterations total
  stage(0, 0);
  run_qtile(31 - pr);
  stage(0, 0);
  run_qtile(pr);
}

// ---------------- launch ----------------
extern "C" void kernel_launch(void* const* d_in, const int* in_sizes, int n_in,
                              void* d_out, int out_size, void* d_ws, size_t ws_size,
                              hipStream_t stream) {
  const float* x = (const float*)d_in[0];
  const float* Wqkv = (const float*)d_in[1];
  const float* Wproj = (const float*)d_in[2];
  const float* qw = (const float*)d_in[3];
  const float* kw = (const float*)d_in[4];
  float* out = (float*)d_out;

  char* ws = (char*)d_ws;
  unsigned short* xb = (unsigned short*)ws;        ws += (size_t)8192 * 1024 * 2;
  unsigned short* wqkvt = (unsigned short*)ws;     ws += (size_t)3072 * 1024 * 2;
  unsigned short* wprojt = (unsigned short*)ws;    ws += (size_t)1024 * 1024 * 2;
  unsigned short* Qr = (unsigned short*)ws;        ws += (size_t)64 * 2048 * 64 * 2;
  unsigned short* Kr = (unsigned short*)ws;        ws += (size_t)64 * 2048 * 64 * 2;
  unsigned short* Vtg = (unsigned short*)ws;       ws += (size_t)64 * 64 * 2048 * 2;
  unsigned short* yb = (unsigned short*)ws;        ws += (size_t)8192 * 1024 * 2;
  float* cosTT = (float*)ws;                       ws += (size_t)32 * 2048 * 4;
  float* sinTT = (float*)ws;                       ws += (size_t)32 * 2048 * 4;

  cvt_f32_bf16<<<2048, 256, 0, stream>>>(x, xb, 8192 * 1024 / 4);
  transpose_f32_bf16<<<dim3(48, 16), 256, 0, stream>>>(Wqkv, wqkvt, 1024, 3072);
  transpose_f32_bf16<<<dim3(16, 16), 256, 0, stream>>>(Wproj, wprojt, 1024, 1024);
  rope_tabT<<<256, 256, 0, stream>>>(cosTT, sinTT);
  gemm_qkvW<<<dim3(24, 32), 256, 0, stream>>>(xb, wqkvt, qw, kw, cosTT, sinTT, Qr, Kr, Vtg);
  attn_fwd<<<dim3(64, 16), 256, 0, stream>>>(Qr, Kr, Vtg, yb);
  gemm_ring<float><<<dim3(8, 64), 256, 0, stream>>>(yb, wprojt, out, 8192, 1024, 1024);
}

// Round 19
// 178.935 us; speedup vs baseline: 1.4708x; 1.0389x over previous
//
#include <hip/hip_runtime.h>
#include <cstdint>
#include <type_traits>

// ---------------- common types / helpers ----------------
typedef __attribute__((ext_vector_type(8))) short bf16x8;   // 8 bf16 in 4 VGPRs
typedef __attribute__((ext_vector_type(4))) float f32x4;

typedef unsigned int __attribute__((address_space(1))) as1_uint;
typedef unsigned int __attribute__((address_space(3))) as3_uint;

__device__ __forceinline__ void llds16(const void* g, void* l) {
  // async global->LDS, 16B per lane; LDS dst is wave-uniform base + lane*16
  __builtin_amdgcn_global_load_lds((const as1_uint*)g, (as3_uint*)l, 16, 0, 0);
}

__device__ __forceinline__ unsigned short f2bf(float f) {
  unsigned int u = __builtin_bit_cast(unsigned int, f);
  u = (u + 0x7fffu + ((u >> 16) & 1u)) >> 16;   // RNE
  return (unsigned short)u;
}
__device__ __forceinline__ float bf2f(unsigned short h) {
  unsigned int u = ((unsigned int)h) << 16;
  return __builtin_bit_cast(float, u);
}

#define MEMBAR() asm volatile("" ::: "memory")

// ---------------- fused prep: cvt + Wqkv^T + Wproj^T + RoPE tables ----------------
// 1D grid of 3328 blocks x 256 threads, branched by block range:
//   [0,2048)    : x f32 -> bf16 (grid-stride over 2M float4)
//   [2048,2816) : Wqkv [1024][3072] f32 -> wqkvt [3072][1024] bf16 (48 x 16 tiles)
//   [2816,3072) : Wproj [1024][1024] f32 -> wprojt (16 x 16 tiles)
//   [3072,3328) : transposed RoPE tables cos/sin [32][2048]
__global__ __launch_bounds__(256) void prep_fused(const float* __restrict__ x,
                                                  const float* __restrict__ Wqkv,
                                                  const float* __restrict__ Wproj,
                                                  unsigned short* __restrict__ xb,
                                                  unsigned short* __restrict__ wqkvt,
                                                  unsigned short* __restrict__ wprojt,
                                                  float* __restrict__ cosT,
                                                  float* __restrict__ sinT) {
  __shared__ float tile[64][65];
  const int bid = blockIdx.x;
  const int t = threadIdx.x;

  if (bid < 2048) {
    // ---- cvt f32 -> bf16, 8192*1024 elements as float4 ----
    const int n4 = 8192 * 1024 / 4;
    int i = bid * 256 + t;
    const int stride = 2048 * 256;
    for (; i < n4; i += stride) {
      float4 v = ((const float4*)x)[i];
      uint2 p;
      p.x = (unsigned)f2bf(v.x) | ((unsigned)f2bf(v.y) << 16);
      p.y = (unsigned)f2bf(v.z) | ((unsigned)f2bf(v.w) << 16);
      ((uint2*)xb)[i] = p;
    }
    return;
  }

  // ---- transpose branches share this body ----
  const float* W;
  unsigned short* Wt;
  int K, N, bx, by;
  if (bid < 2816) {
    int idx = bid - 2048;               // 768 = 48 x 16
    W = Wqkv; Wt = wqkvt; K = 1024; N = 3072;
    bx = idx % 48; by = idx / 48;
  } else if (bid < 3072) {
    int idx = bid - 2816;               // 256 = 16 x 16
    W = Wproj; Wt = wprojt; K = 1024; N = 1024;
    bx = idx % 16; by = idx / 16;
  } else {
    // ---- RoPE tables (transposed [32][2048]) ----
    int i = (bid - 3072) * 256 + t;     // < 65536
    int dm = i >> 11, tt = i & 2047;
    float inv = powf(10000.0f, -(float)dm * (1.0f / 32.0f));
    float a = (float)tt * inv;
    cosT[i] = cosf(a);
    sinT[i] = sinf(a);
    return;
  }

  int n0 = bx * 64, k0 = by * 64;
  int lr = t >> 4, lc = (t & 15) * 4;
#pragma unroll
  for (int i = 0; i < 4; ++i) {
    int k = lr + i * 16;
    float4 v = *(const float4*)&W[(size_t)(k0 + k) * N + n0 + lc];
    tile[k][lc] = v.x; tile[k][lc + 1] = v.y; tile[k][lc + 2] = v.z; tile[k][lc + 3] = v.w;
  }
  __syncthreads();
  int n = t >> 2, kc = (t & 3) * 16;
  unsigned short* dst = &Wt[(size_t)(n0 + n) * K + k0 + kc];
#pragma unroll
  for (int j = 0; j < 16; ++j) dst[j] = f2bf(tile[kc + j][n]);
}

// B-panel-hot XCD block mapping (requires gridDim.y % 8 == 0)
__device__ __forceinline__ void block_map(int& bx, int& by) {
  const int lin = blockIdx.y * gridDim.x + blockIdx.x;
  const int xcd = lin & 7;
  const int idx = lin >> 3;
  const int ych = gridDim.y >> 3;
  by = xcd * ych + (idx & (ych - 1));
  bx = idx / ych;
}

// ---------------- ring-3 NT GEMM (proj): C[M][N] = A[M][K] * Bt[N][K]^T --------------
// vmcnt(4) steady-state; vmcnt(0) on the FINAL iteration.
template <typename OutT>
__global__ __launch_bounds__(256) void gemm_ring(const unsigned short* __restrict__ A,
                                                 const unsigned short* __restrict__ Bt,
                                                 OutT* __restrict__ C, int M, int N, int K) {
  __shared__ unsigned short As[3][128 * 32];
  __shared__ unsigned short Bs[3][128 * 32];
  const int tid = threadIdx.x;
  const int w = tid >> 6, lane = tid & 63;
  const int l15 = lane & 15, lg = lane >> 4;
  const int wr = w >> 1, wc = w & 1;

  int bx, by;
  block_map(bx, by);
  const int m0 = by * 128, n0 = bx * 128;

  const size_t K2 = (size_t)K * 2;
  const char* Ag = (const char*)A;
  const char* Bg = (const char*)Bt;
  const int rc = lane >> 2;            // row within chunk 0..15
  const int cb = (lane & 3) * 16;      // byte col within row

  auto stage = [&](int buf, int kt) {
#pragma unroll
    for (int i = 0; i < 2; ++i) {
      int c = w + i * 4;
      int row = c * 16 + rc;
      int srcc = cb ^ (((row >> 1) & 3) << 4);
      size_t kofs = (size_t)kt * 64 + srcc;
      llds16(Ag + (size_t)(m0 + row) * K2 + kofs, (char*)&As[buf][0] + c * 1024);
      llds16(Bg + (size_t)(n0 + row) * K2 + kofs, (char*)&Bs[buf][0] + c * 1024);
    }
  };

  f32x4 acc[4][4] = {};
  const int nk = K >> 5;
  stage(0, 0);
  stage(1, 1);
  int cur = 0;
  for (int t = 0; t < nk; ++t) {
    if (t + 1 < nk) asm volatile("s_waitcnt vmcnt(4)" ::: "memory");
    else            asm volatile("s_waitcnt vmcnt(0)" ::: "memory");
    __builtin_amdgcn_s_barrier();
    MEMBAR();
    if (t + 2 < nk) stage(cur + 2 >= 3 ? cur - 1 : cur + 2, t + 2);

    const unsigned short* Ab = &As[cur][0];
    const unsigned short* Bb = &Bs[cur][0];
    bf16x8 af[4], bfr[4];
#pragma unroll
    for (int m = 0; m < 4; ++m) {
      int row = wr * 64 + m * 16 + l15;
      af[m] = *(const bf16x8*)((const char*)Ab + row * 64 + ((lg * 16) ^ (((row >> 1) & 3) << 4)));
    }
#pragma unroll
    for (int n = 0; n < 4; ++n) {
      int row = wc * 64 + n * 16 + l15;
      bfr[n] = *(const bf16x8*)((const char*)Bb + row * 64 + ((lg * 16) ^ (((row >> 1) & 3) << 4)));
    }
#pragma unroll
    for (int m = 0; m < 4; ++m)
#pragma unroll
      for (int n = 0; n < 4; ++n)
        acc[m][n] = __builtin_amdgcn_mfma_f32_16x16x32_bf16(af[m], bfr[n], acc[m][n], 0, 0, 0);
    cur = (cur == 2) ? 0 : cur + 1;
  }

#pragma unroll
  for (int m = 0; m < 4; ++m)
#pragma unroll
    for (int n = 0; n < 4; ++n) {
      int row = m0 + wr * 64 + m * 16 + lg * 4;
      int col = n0 + wc * 64 + n * 16 + l15;
#pragma unroll
      for (int r = 0; r < 4; ++r) {
        if constexpr (std::is_same<OutT, float>::value)
          C[(size_t)(row + r) * N + col] = acc[m][n][r];
        else
          C[(size_t)(row + r) * N + col] = f2bf(acc[m][n][r]);
      }
    }
}

// ---------------- WIDE-WAVE fused QKV GEMM (ring-3, distance-2; R13/R15, 90 us) ----
__global__ __launch_bounds__(256, 2) void gemm_qkvW(const unsigned short* __restrict__ A,
                                                    const unsigned short* __restrict__ Bt,
                                                    const float* __restrict__ qw,
                                                    const float* __restrict__ kw,
                                                    const float* __restrict__ cosTT,
                                                    const float* __restrict__ sinTT,
                                                    unsigned short* __restrict__ Qr,
                                                    unsigned short* __restrict__ Kr,
                                                    unsigned short* __restrict__ Vtg) {
  constexpr int K = 1024;
  constexpr int nk = K >> 5;                  // 32 K-tiles of 32
  __shared__ unsigned short smem[36864];      // 72 KB: 3 x (A 16KB + B 8KB)
  char* base = (char*)smem;

  const int tid = threadIdx.x;
  const int w = tid >> 6, lane = tid & 63;
  const int l15 = lane & 15, lg = lane >> 4;
  const int wr = w >> 1, wc = w & 1;

  int bx, by;
  block_map(bx, by);                          // grid dim3(24, 32)
  const int m0 = by * 256, n0 = bx * 128;

  const size_t K2 = (size_t)K * 2;
  const char* Ag = (const char*)A;
  const char* Bg = (const char*)Bt;
  const int rc4 = tid >> 2;                   // row within 64-row chunk
  const int cb = (tid & 3) * 16;              // byte col within 64B row

  auto stage = [&](int buf, int kt) {
    char* ab = base + buf * 24576;
#pragma unroll
    for (int j = 0; j < 4; ++j) {             // A: 256 rows
      int row = j * 64 + rc4;
      int srcc = cb ^ (((row >> 1) & 3) << 4);
      llds16(Ag + (size_t)(m0 + row) * K2 + (size_t)kt * 64 + srcc,
             ab + j * 4096 + tid * 16);
    }
#pragma unroll
    for (int j = 0; j < 2; ++j) {             // B: 128 rows
      int row = j * 64 + rc4;
      int srcc = cb ^ (((row >> 1) & 3) << 4);
      llds16(Bg + (size_t)(n0 + row) * K2 + (size_t)kt * 64 + srcc,
             ab + 16384 + j * 4096 + tid * 16);
    }
  };

  f32x4 acc[8][4] = {};
  stage(0, 0);
  stage(1, 1);
  int cur = 0;
  for (int t = 0; t < nk; ++t) {
    if (t + 1 < nk) asm volatile("s_waitcnt vmcnt(6)" ::: "memory");
    else            asm volatile("s_waitcnt vmcnt(0)" ::: "memory");
    __builtin_amdgcn_s_barrier();
    MEMBAR();
    if (t + 2 < nk) stage(cur + 2 >= 3 ? cur - 1 : cur + 2, t + 2);

    const char* Ab = base + cur * 24576;
    const char* Bb = Ab + 16384;
    bf16x8 af[8], bfr[4];
#pragma unroll
    for (int m = 0; m < 8; ++m) {
      int row = wr * 128 + m * 16 + l15;
      af[m] = *(const bf16x8*)(Ab + row * 64 + ((lg * 16) ^ (((row >> 1) & 3) << 4)));
    }
#pragma unroll
    for (int n = 0; n < 4; ++n) {
      int row = wc * 64 + n * 16 + l15;
      bfr[n] = *(const bf16x8*)(Bb + row * 64 + ((lg * 16) ^ (((row >> 1) & 3) << 4)));
    }
    __builtin_amdgcn_s_setprio(1);
#pragma unroll
    for (int m = 0; m < 8; ++m)
#pragma unroll
      for (int n = 0; n < 4; ++n)
        acc[m][n] = __builtin_amdgcn_mfma_f32_16x16x32_bf16(af[m], bfr[n], acc[m][n], 0, 0, 0);
    __builtin_amdgcn_s_setprio(0);
    cur = (cur == 2) ? 0 : cur + 1;
  }

  __syncthreads();                            // K-loop LDS traffic done; reuse as bounce

  // ---- fused epilogue (two 64-row chunks) ----
  const int head2 = bx * 2 + wc;              // 0..47
  const int cls = head2 >> 4;                 // 0=Q, 1=K, 2=V
  const int head = head2 & 15;
  const int rowb = m0 + wr * 128;
  const int b = rowb >> 11;
  const int tl = rowb & 2047;
  const int bh = b * 16 + head;
  unsigned short* tb = smem + w * 4864;       // per-wave 9728 B bounce tile (64 x 76)

  if (cls < 2) {
    const float* wt = cls ? kw : qw;
    const float scale = cls ? 1.0f : 0.18033688011112042f;   // log2(e)/8 folded into Q
    unsigned short* outp = cls ? Kr : Qr;
    float wv[4];
#pragma unroll
    for (int n = 0; n < 4; ++n) wv[n] = wt[n * 16 + l15];
    const float* c0p = cosTT + l15 * 2048;
    const float* c1p = cosTT + (16 + l15) * 2048;
    const float* s0p = sinTT + l15 * 2048;
    const float* s1p = sinTT + (16 + l15) * 2048;
#pragma unroll
    for (int chunk = 0; chunk < 2; ++chunk) {
#pragma unroll
      for (int q = 0; q < 4; ++q) {
        const int m = chunk * 4 + q;
        int t0 = tl + m * 16 + lg * 4;
        f32x4 ssq = {};
#pragma unroll
        for (int n = 0; n < 4; ++n) ssq += acc[m][n] * acc[m][n];
#pragma unroll
        for (int r = 0; r < 4; ++r) {
          float v = ssq[r];
          v += __shfl_xor(v, 1); v += __shfl_xor(v, 2);
          v += __shfl_xor(v, 4); v += __shfl_xor(v, 8);
          ssq[r] = rsqrtf(v * (1.0f / 64.0f) + 1e-5f) * scale;
        }
        f32x4 nv[4];
#pragma unroll
        for (int n = 0; n < 4; ++n) nv[n] = acc[m][n] * ssq * wv[n];
        f32x4 cv0 = *(const f32x4*)(c0p + t0);
        f32x4 cv1 = *(const f32x4*)(c1p + t0);
        f32x4 sv0 = *(const f32x4*)(s0p + t0);
        f32x4 sv1 = *(const f32x4*)(s1p + t0);
        f32x4 ov[4];
        ov[0] = nv[0] * cv0 - nv[2] * sv0;
        ov[1] = nv[1] * cv1 - nv[3] * sv1;
        ov[2] = nv[2] * cv0 + nv[0] * sv0;
        ov[3] = nv[3] * cv1 + nv[1] * sv1;
        int tloc = q * 16 + lg * 4;
#pragma unroll
        for (int n = 0; n < 4; ++n)
#pragma unroll
          for (int r = 0; r < 4; ++r)
            tb[(tloc + r) * 76 + n * 16 + l15] = f2bf(ov[n][r]);
      }
      MEMBAR();                               // per-wave LDS in-order
      const int t = lane;
      unsigned short* yp = outp + ((size_t)bh * 2048 + tl + chunk * 64 + t) * 64;
#pragma unroll
      for (int j = 0; j < 8; ++j)
        *(bf16x8*)(yp + j * 8) = *(const bf16x8*)(tb + t * 76 + j * 8);
      MEMBAR();                               // bounce reads before next chunk's writes
    }
  } else {
#pragma unroll
    for (int chunk = 0; chunk < 2; ++chunk) {
#pragma unroll
      for (int q = 0; q < 4; ++q) {
        const int m = chunk * 4 + q;
#pragma unroll
        for (int n = 0; n < 4; ++n) {
          int d = n * 16 + l15, tloc = q * 16 + lg * 4;
          ushort4 pk;
          pk.x = f2bf(acc[m][n][0]); pk.y = f2bf(acc[m][n][1]);
          pk.z = f2bf(acc[m][n][2]); pk.w = f2bf(acc[m][n][3]);
          *(ushort4*)(tb + d * 76 + tloc) = pk;
        }
      }
      MEMBAR();
      int d2 = lane;
      unsigned short* vp = Vtg + ((size_t)bh * 64 + d2) * 2048 + tl + chunk * 64;
#pragma unroll
      for (int j = 0; j < 8; ++j) {
        bf16x8 vv = *(const bf16x8*)(tb + d2 * 76 + j * 8);
        *(bf16x8*)(vp + j * 8) = vv;
      }
      MEMBAR();
    }
  }
}

// ---------------- causal flash attention: QBLK=64, counted-vmcnt no-drain loop -------
// (R15 version, verified, best measured)
__global__ __launch_bounds__(256) void attn_fwd(const unsigned short* __restrict__ Q,
                                                const unsigned short* __restrict__ K,
                                                const unsigned short* __restrict__ Vtg,
                                                unsigned short* __restrict__ Y) {
  const int bh = blockIdx.x;        // 0..63
  const int pr = blockIdx.y;        // 0..15
  const int b = bh >> 4, h = bh & 15;
  const int tid = threadIdx.x;
  const int w = tid >> 6, lane = tid & 63;
  const int l15 = lane & 15, lg = lane >> 4;

  __shared__ unsigned short Kl[2][64 * 64];   // swizzled [k][d], 128B rows (16384 B)
  __shared__ unsigned short Vt[2][64 * 64];   // swizzled [d][k], 128B rows (16384 B)
  __shared__ unsigned short Pl[4][16 * 64];   // per-wave P^T [q][k], 128B rows, swz (8192 B)

  const size_t bhT = (size_t)bh * 2048;
  const char* Kg = (const char*)(K + bhT * 64);          // row stride 128B
  const char* Vg = (const char*)(Vtg + bhT * 64);        // row stride 4096B

  auto stage = [&](int buf, int kt) {
#pragma unroll
    for (int i = 0; i < 2; ++i) {
      int c = w * 2 + i;                     // chunk 0..7, wave-uniform
      int pos = c * 1024 + lane * 16;        // linear byte in 8KB tile
      int row = pos >> 7, cb = pos & 127;
      int srcb = cb ^ ((row & 7) << 4);      // inverse-swizzled source
      llds16(Kg + ((size_t)(kt * 64 + row)) * 128 + srcb,
             (char*)&Kl[buf][0] + c * 1024);
      llds16(Vg + (size_t)row * 4096 + (size_t)kt * 128 + srcb,
             (char*)&Vt[buf][0] + c * 1024);
    }
  };

  auto run_qtile = [&](int qtb) {
    const int qbase = qtb * 64;
    const unsigned short* Qp = Q + (bhT + qbase + w * 16 + l15) * 64 + lg * 8;
    bf16x8 aq[2];
    aq[0] = *(const bf16x8*)(Qp);
    aq[1] = *(const bf16x8*)(Qp + 32);

    f32x4 o[4] = {};        // O^T: lane q=l15, rows d = df*16 + lg*4 + r
    float psum = 0.0f;      // per-lane (q = l15) partial sum over its k slice

    char* Pw = (char*)&Pl[w][0];
    const int psw = (l15 & 7) << 4;       // 16B-granular XOR swizzle keyed by q-row

    for (int kt = 0; kt <= qtb; ++kt) {
      const int cur = kt & 1;
      if (kt < qtb) {
        stage(cur ^ 1, kt + 1);           // issue next tile: my 4 loads
        asm volatile("s_waitcnt vmcnt(4)" ::: "memory");   // wait MY tile-t loads
      } else {
        asm volatile("s_waitcnt vmcnt(0)" ::: "memory");   // final iter: drain
      }
      __builtin_amdgcn_s_barrier();       // all waves' tile-t loads now visible
      MEMBAR();
      const char* Kc = (const char*)&Kl[cur][0];
      const char* Vc = (const char*)&Vt[cur][0];

      f32x4 s[4] = {};      // S^T: lane q=l15, rows k = n*16 + lg*4 + r
      __builtin_amdgcn_s_setprio(1);
#pragma unroll
      for (int n = 0; n < 4; ++n) {
        int r = n * 16 + l15, sw = (r & 7) << 4;
#pragma unroll
        for (int ks = 0; ks < 2; ++ks) {
          bf16x8 bk = *(const bf16x8*)(Kc + r * 128 + ((ks * 64 + lg * 16) ^ sw));
          s[n] = __builtin_amdgcn_mfma_f32_16x16x32_bf16(bk, aq[ks], s[n], 0, 0, 0);
        }
      }
      __builtin_amdgcn_s_setprio(0);

      if (kt == qtb) {   // diagonal tile: causal mask (k_local > q_local)
#pragma unroll
        for (int n = 0; n < 4; ++n)
#pragma unroll
          for (int r = 0; r < 4; ++r)
            if (n * 16 + lg * 4 + r > w * 16 + l15) s[n][r] = -1e30f;
      }

      // p = exp2(s); per-lane psum; truncation-pack pairs -> b64 LDS writes
#pragma unroll
      for (int n = 0; n < 4; ++n) {
        float p0 = __builtin_exp2f(s[n][0]);
        float p1 = __builtin_exp2f(s[n][1]);
        float p2 = __builtin_exp2f(s[n][2]);
        float p3 = __builtin_exp2f(s[n][3]);
        psum += (p0 + p1) + (p2 + p3);
        unsigned u0 = __builtin_bit_cast(unsigned, p0);
        unsigned u1 = __builtin_bit_cast(unsigned, p1);
        unsigned u2 = __builtin_bit_cast(unsigned, p2);
        unsigned u3 = __builtin_bit_cast(unsigned, p3);
        uint2 pk;
        pk.x = (u0 >> 16) | (u1 & 0xffff0000u);
        pk.y = (u2 >> 16) | (u3 & 0xffff0000u);
        *(uint2*)(Pw + l15 * 128 + ((n * 32 + lg * 8) ^ psw)) = pk;
      }
      MEMBAR();  // keep P stores before P reads (per-wave LDS in-order)

      bf16x8 ap[2];
      ap[0] = *(const bf16x8*)(Pw + l15 * 128 + ((lg * 16) ^ psw));
      ap[1] = *(const bf16x8*)(Pw + l15 * 128 + ((64 + lg * 16) ^ psw));

      __builtin_amdgcn_s_setprio(1);
#pragma unroll
      for (int df = 0; df < 4; ++df) {
        int rr = df * 16 + l15, sw = (rr & 7) << 4;
#pragma unroll
        for (int ks = 0; ks < 2; ++ks) {
          bf16x8 bv = *(const bf16x8*)(Vc + rr * 128 + ((ks * 64 + lg * 16) ^ sw));
          o[df] = __builtin_amdgcn_mfma_f32_16x16x32_bf16(bv, ap[ks], o[df], 0, 0, 0);
        }
      }
      __builtin_amdgcn_s_setprio(0);
      MEMBAR();
      __builtin_amdgcn_s_barrier();       // all waves done reading before restage
      MEMBAR();
    }

    // full row-sum: combine the 4 lanes sharing this q (lg differs in bits 4..5)
    psum += __shfl_xor(psum, 16);
    psum += __shfl_xor(psum, 32);
    float inv = 1.0f / psum;

    size_t q = qbase + w * 16 + l15;
    unsigned short* yp = Y + ((size_t)b * 2048 + q) * 1024 + h * 64 + lg * 4;
#pragma unroll
    for (int df = 0; df < 4; ++df) {
      ushort4 v;
      v.x = f2bf(o[df][0] * inv);
      v.y = f2bf(o[df][1] * inv);
      v.z = f2bf(o[df][2] * inv);
      v.w = f2bf(o[df][3] * inv);
      *(ushort4*)(yp + df * 16) = v;
    }
  };

  // heavy segment then light segment; every block: 33 kv-tile iterations total
  stage(0, 0);
  run_qtile(31 - pr);
  stage(0, 0);
  run_qtile(pr);
}

// ---------------- launch ----------------
extern "C" void kernel_launch(void* const* d_in, const int* in_sizes, int n_in,
                              void* d_out, int out_size, void* d_ws, size_t ws_size,
                              hipStream_t stream) {
  const float* x = (const float*)d_in[0];
  const float* Wqkv = (const float*)d_in[1];
  const float* Wproj = (const float*)d_in[2];
  const float* qw = (const float*)d_in[3];
  const float* kw = (const float*)d_in[4];
  float* out = (float*)d_out;

  char* ws = (char*)d_ws;
  unsigned short* xb = (unsigned short*)ws;        ws += (size_t)8192 * 1024 * 2;
  unsigned short* wqkvt = (unsigned short*)ws;     ws += (size_t)3072 * 1024 * 2;
  unsigned short* wprojt = (unsigned short*)ws;    ws += (size_t)1024 * 1024 * 2;
  unsigned short* Qr = (unsigned short*)ws;        ws += (size_t)64 * 2048 * 64 * 2;
  unsigned short* Kr = (unsigned short*)ws;        ws += (size_t)64 * 2048 * 64 * 2;
  unsigned short* Vtg = (unsigned short*)ws;       ws += (size_t)64 * 64 * 2048 * 2;
  unsigned short* yb = (unsigned short*)ws;        ws += (size_t)8192 * 1024 * 2;
  float* cosTT = (float*)ws;                       ws += (size_t)32 * 2048 * 4;
  float* sinTT = (float*)ws;                       ws += (size_t)32 * 2048 * 4;

  prep_fused<<<3328, 256, 0, stream>>>(x, Wqkv, Wproj, xb, wqkvt, wprojt, cosTT, sinTT);
  gemm_qkvW<<<dim3(24, 32), 256, 0, stream>>>(xb, wqkvt, qw, kw, cosTT, sinTT, Qr, Kr, Vtg);
  attn_fwd<<<dim3(64, 16), 256, 0, stream>>>(Qr, Kr, Vtg, yb);
  gemm_ring<float><<<dim3(8, 64), 256, 0, stream>>>(yb, wprojt, out, 8192, 1024, 1024);
}

// Round 20
// 178.860 us; speedup vs baseline: 1.4714x; 1.0004x over previous
//
#include <hip/hip_runtime.h>
#include <cstdint>
#include <type_traits>

// ---------------- common types / helpers ----------------
typedef __attribute__((ext_vector_type(8))) short bf16x8;   // 8 bf16 in 4 VGPRs
typedef __attribute__((ext_vector_type(4))) float f32x4;

typedef unsigned int __attribute__((address_space(1))) as1_uint;
typedef unsigned int __attribute__((address_space(3))) as3_uint;

__device__ __forceinline__ void llds16(const void* g, void* l) {
  // async global->LDS, 16B per lane; LDS dst is wave-uniform base + lane*16
  __builtin_amdgcn_global_load_lds((const as1_uint*)g, (as3_uint*)l, 16, 0, 0);
}

__device__ __forceinline__ unsigned short f2bf(float f) {
  unsigned int u = __builtin_bit_cast(unsigned int, f);
  u = (u + 0x7fffu + ((u >> 16) & 1u)) >> 16;   // RNE
  return (unsigned short)u;
}
__device__ __forceinline__ float bf2f(unsigned short h) {
  unsigned int u = ((unsigned int)h) << 16;
  return __builtin_bit_cast(float, u);
}

#define MEMBAR() asm volatile("" ::: "memory")

// ---------------- fused prep: cvt + Wqkv^T + Wproj^T + RoPE tables ----------------
// 1D grid of 3328 blocks x 256 threads, branched by block range:
//   [0,2048)    : x f32 -> bf16 (grid-stride over 2M float4)
//   [2048,2816) : Wqkv [1024][3072] f32 -> wqkvt [3072][1024] bf16 (48 x 16 tiles)
//   [2816,3072) : Wproj [1024][1024] f32 -> wprojt (16 x 16 tiles)
//   [3072,3328) : transposed RoPE tables cos/sin [32][2048]
__global__ __launch_bounds__(256) void prep_fused(const float* __restrict__ x,
                                                  const float* __restrict__ Wqkv,
                                                  const float* __restrict__ Wproj,
                                                  unsigned short* __restrict__ xb,
                                                  unsigned short* __restrict__ wqkvt,
                                                  unsigned short* __restrict__ wprojt,
                                                  float* __restrict__ cosT,
                                                  float* __restrict__ sinT) {
  __shared__ float tile[64][65];
  const int bid = blockIdx.x;
  const int t = threadIdx.x;

  if (bid < 2048) {
    // ---- cvt f32 -> bf16, 8192*1024 elements as float4 ----
    const int n4 = 8192 * 1024 / 4;
    int i = bid * 256 + t;
    const int stride = 2048 * 256;
    for (; i < n4; i += stride) {
      float4 v = ((const float4*)x)[i];
      uint2 p;
      p.x = (unsigned)f2bf(v.x) | ((unsigned)f2bf(v.y) << 16);
      p.y = (unsigned)f2bf(v.z) | ((unsigned)f2bf(v.w) << 16);
      ((uint2*)xb)[i] = p;
    }
    return;
  }

  // ---- transpose branches share this body ----
  const float* W;
  unsigned short* Wt;
  int K, N, bx, by;
  if (bid < 2816) {
    int idx = bid - 2048;               // 768 = 48 x 16
    W = Wqkv; Wt = wqkvt; K = 1024; N = 3072;
    bx = idx % 48; by = idx / 48;
  } else if (bid < 3072) {
    int idx = bid - 2816;               // 256 = 16 x 16
    W = Wproj; Wt = wprojt; K = 1024; N = 1024;
    bx = idx % 16; by = idx / 16;
  } else {
    // ---- RoPE tables (transposed [32][2048]) ----
    int i = (bid - 3072) * 256 + t;     // < 65536
    int dm = i >> 11, tt = i & 2047;
    float inv = powf(10000.0f, -(float)dm * (1.0f / 32.0f));
    float a = (float)tt * inv;
    cosT[i] = cosf(a);
    sinT[i] = sinf(a);
    return;
  }

  int n0 = bx * 64, k0 = by * 64;
  int lr = t >> 4, lc = (t & 15) * 4;
#pragma unroll
  for (int i = 0; i < 4; ++i) {
    int k = lr + i * 16;
    float4 v = *(const float4*)&W[(size_t)(k0 + k) * N + n0 + lc];
    tile[k][lc] = v.x; tile[k][lc + 1] = v.y; tile[k][lc + 2] = v.z; tile[k][lc + 3] = v.w;
  }
  __syncthreads();
  int n = t >> 2, kc = (t & 3) * 16;
  unsigned short* dst = &Wt[(size_t)(n0 + n) * K + k0 + kc];
#pragma unroll
  for (int j = 0; j < 16; ++j) dst[j] = f2bf(tile[kc + j][n]);
}

// B-panel-hot XCD block mapping (requires gridDim.y % 8 == 0)
__device__ __forceinline__ void block_map(int& bx, int& by) {
  const int lin = blockIdx.y * gridDim.x + blockIdx.x;
  const int xcd = lin & 7;
  const int idx = lin >> 3;
  const int ych = gridDim.y >> 3;
  by = xcd * ych + (idx & (ych - 1));
  bx = idx / ych;
}

// ---------------- ring-3 NT GEMM (proj): C[M][N] = A[M][K] * Bt[N][K]^T --------------
// vmcnt(4) steady-state; vmcnt(0) on the FINAL iteration.
template <typename OutT>
__global__ __launch_bounds__(256) void gemm_ring(const unsigned short* __restrict__ A,
                                                 const unsigned short* __restrict__ Bt,
                                                 OutT* __restrict__ C, int M, int N, int K) {
  __shared__ unsigned short As[3][128 * 32];
  __shared__ unsigned short Bs[3][128 * 32];
  const int tid = threadIdx.x;
  const int w = tid >> 6, lane = tid & 63;
  const int l15 = lane & 15, lg = lane >> 4;
  const int wr = w >> 1, wc = w & 1;

  int bx, by;
  block_map(bx, by);
  const int m0 = by * 128, n0 = bx * 128;

  const size_t K2 = (size_t)K * 2;
  const char* Ag = (const char*)A;
  const char* Bg = (const char*)Bt;
  const int rc = lane >> 2;            // row within chunk 0..15
  const int cb = (lane & 3) * 16;      // byte col within row

  auto stage = [&](int buf, int kt) {
#pragma unroll
    for (int i = 0; i < 2; ++i) {
      int c = w + i * 4;
      int row = c * 16 + rc;
      int srcc = cb ^ (((row >> 1) & 3) << 4);
      size_t kofs = (size_t)kt * 64 + srcc;
      llds16(Ag + (size_t)(m0 + row) * K2 + kofs, (char*)&As[buf][0] + c * 1024);
      llds16(Bg + (size_t)(n0 + row) * K2 + kofs, (char*)&Bs[buf][0] + c * 1024);
    }
  };

  f32x4 acc[4][4] = {};
  const int nk = K >> 5;
  stage(0, 0);
  stage(1, 1);
  int cur = 0;
  for (int t = 0; t < nk; ++t) {
    if (t + 1 < nk) asm volatile("s_waitcnt vmcnt(4)" ::: "memory");
    else            asm volatile("s_waitcnt vmcnt(0)" ::: "memory");
    __builtin_amdgcn_s_barrier();
    MEMBAR();
    if (t + 2 < nk) stage(cur + 2 >= 3 ? cur - 1 : cur + 2, t + 2);

    const unsigned short* Ab = &As[cur][0];
    const unsigned short* Bb = &Bs[cur][0];
    bf16x8 af[4], bfr[4];
#pragma unroll
    for (int m = 0; m < 4; ++m) {
      int row = wr * 64 + m * 16 + l15;
      af[m] = *(const bf16x8*)((const char*)Ab + row * 64 + ((lg * 16) ^ (((row >> 1) & 3) << 4)));
    }
#pragma unroll
    for (int n = 0; n < 4; ++n) {
      int row = wc * 64 + n * 16 + l15;
      bfr[n] = *(const bf16x8*)((const char*)Bb + row * 64 + ((lg * 16) ^ (((row >> 1) & 3) << 4)));
    }
#pragma unroll
    for (int m = 0; m < 4; ++m)
#pragma unroll
      for (int n = 0; n < 4; ++n)
        acc[m][n] = __builtin_amdgcn_mfma_f32_16x16x32_bf16(af[m], bfr[n], acc[m][n], 0, 0, 0);
    cur = (cur == 2) ? 0 : cur + 1;
  }

#pragma unroll
  for (int m = 0; m < 4; ++m)
#pragma unroll
    for (int n = 0; n < 4; ++n) {
      int row = m0 + wr * 64 + m * 16 + lg * 4;
      int col = n0 + wc * 64 + n * 16 + l15;
#pragma unroll
      for (int r = 0; r < 4; ++r) {
        if constexpr (std::is_same<OutT, float>::value)
          C[(size_t)(row + r) * N + col] = acc[m][n][r];
        else
          C[(size_t)(row + r) * N + col] = f2bf(acc[m][n][r]);
      }
    }
}

// ---------------- WIDE-WAVE fused QKV GEMM (ring-3, distance-2; best measured) ----
__global__ __launch_bounds__(256, 2) void gemm_qkvW(const unsigned short* __restrict__ A,
                                                    const unsigned short* __restrict__ Bt,
                                                    const float* __restrict__ qw,
                                                    const float* __restrict__ kw,
                                                    const float* __restrict__ cosTT,
                                                    const float* __restrict__ sinTT,
                                                    unsigned short* __restrict__ Qr,
                                                    unsigned short* __restrict__ Kr,
                                                    unsigned short* __restrict__ Vtg) {
  constexpr int K = 1024;
  constexpr int nk = K >> 5;                  // 32 K-tiles of 32
  __shared__ unsigned short smem[36864];      // 72 KB: 3 x (A 16KB + B 8KB)
  char* base = (char*)smem;

  const int tid = threadIdx.x;
  const int w = tid >> 6, lane = tid & 63;
  const int l15 = lane & 15, lg = lane >> 4;
  const int wr = w >> 1, wc = w & 1;

  int bx, by;
  block_map(bx, by);                          // grid dim3(24, 32)
  const int m0 = by * 256, n0 = bx * 128;

  const size_t K2 = (size_t)K * 2;
  const char* Ag = (const char*)A;
  const char* Bg = (const char*)Bt;
  const int rc4 = tid >> 2;                   // row within 64-row chunk
  const int cb = (tid & 3) * 16;              // byte col within 64B row

  auto stage = [&](int buf, int kt) {
    char* ab = base + buf * 24576;
#pragma unroll
    for (int j = 0; j < 4; ++j) {             // A: 256 rows
      int row = j * 64 + rc4;
      int srcc = cb ^ (((row >> 1) & 3) << 4);
      llds16(Ag + (size_t)(m0 + row) * K2 + (size_t)kt * 64 + srcc,
             ab + j * 4096 + tid * 16);
    }
#pragma unroll
    for (int j = 0; j < 2; ++j) {             // B: 128 rows
      int row = j * 64 + rc4;
      int srcc = cb ^ (((row >> 1) & 3) << 4);
      llds16(Bg + (size_t)(n0 + row) * K2 + (size_t)kt * 64 + srcc,
             ab + 16384 + j * 4096 + tid * 16);
    }
  };

  f32x4 acc[8][4] = {};
  stage(0, 0);
  stage(1, 1);
  int cur = 0;
  for (int t = 0; t < nk; ++t) {
    if (t + 1 < nk) asm volatile("s_waitcnt vmcnt(6)" ::: "memory");
    else            asm volatile("s_waitcnt vmcnt(0)" ::: "memory");
    __builtin_amdgcn_s_barrier();
    MEMBAR();
    if (t + 2 < nk) stage(cur + 2 >= 3 ? cur - 1 : cur + 2, t + 2);

    const char* Ab = base + cur * 24576;
    const char* Bb = Ab + 16384;
    bf16x8 af[8], bfr[4];
#pragma unroll
    for (int m = 0; m < 8; ++m) {
      int row = wr * 128 + m * 16 + l15;
      af[m] = *(const bf16x8*)(Ab + row * 64 + ((lg * 16) ^ (((row >> 1) & 3) << 4)));
    }
#pragma unroll
    for (int n = 0; n < 4; ++n) {
      int row = wc * 64 + n * 16 + l15;
      bfr[n] = *(const bf16x8*)(Bb + row * 64 + ((lg * 16) ^ (((row >> 1) & 3) << 4)));
    }
    __builtin_amdgcn_s_setprio(1);
#pragma unroll
    for (int m = 0; m < 8; ++m)
#pragma unroll
      for (int n = 0; n < 4; ++n)
        acc[m][n] = __builtin_amdgcn_mfma_f32_16x16x32_bf16(af[m], bfr[n], acc[m][n], 0, 0, 0);
    __builtin_amdgcn_s_setprio(0);
    cur = (cur == 2) ? 0 : cur + 1;
  }

  __syncthreads();                            // K-loop LDS traffic done; reuse as bounce

  // ---- fused epilogue (two 64-row chunks) ----
  const int head2 = bx * 2 + wc;              // 0..47
  const int cls = head2 >> 4;                 // 0=Q, 1=K, 2=V
  const int head = head2 & 15;
  const int rowb = m0 + wr * 128;
  const int b = rowb >> 11;
  const int tl = rowb & 2047;
  const int bh = b * 16 + head;
  unsigned short* tb = smem + w * 4864;       // per-wave 9728 B bounce tile (64 x 76)

  if (cls < 2) {
    const float* wt = cls ? kw : qw;
    const float scale = cls ? 1.0f : 0.18033688011112042f;   // log2(e)/8 folded into Q
    unsigned short* outp = cls ? Kr : Qr;
    float wv[4];
#pragma unroll
    for (int n = 0; n < 4; ++n) wv[n] = wt[n * 16 + l15];
    const float* c0p = cosTT + l15 * 2048;
    const float* c1p = cosTT + (16 + l15) * 2048;
    const float* s0p = sinTT + l15 * 2048;
    const float* s1p = sinTT + (16 + l15) * 2048;
#pragma unroll
    for (int chunk = 0; chunk < 2; ++chunk) {
#pragma unroll
      for (int q = 0; q < 4; ++q) {
        const int m = chunk * 4 + q;
        int t0 = tl + m * 16 + lg * 4;
        f32x4 ssq = {};
#pragma unroll
        for (int n = 0; n < 4; ++n) ssq += acc[m][n] * acc[m][n];
#pragma unroll
        for (int r = 0; r < 4; ++r) {
          float v = ssq[r];
          v += __shfl_xor(v, 1); v += __shfl_xor(v, 2);
          v += __shfl_xor(v, 4); v += __shfl_xor(v, 8);
          ssq[r] = rsqrtf(v * (1.0f / 64.0f) + 1e-5f) * scale;
        }
        f32x4 nv[4];
#pragma unroll
        for (int n = 0; n < 4; ++n) nv[n] = acc[m][n] * ssq * wv[n];
        f32x4 cv0 = *(const f32x4*)(c0p + t0);
        f32x4 cv1 = *(const f32x4*)(c1p + t0);
        f32x4 sv0 = *(const f32x4*)(s0p + t0);
        f32x4 sv1 = *(const f32x4*)(s1p + t0);
        f32x4 ov[4];
        ov[0] = nv[0] * cv0 - nv[2] * sv0;
        ov[1] = nv[1] * cv1 - nv[3] * sv1;
        ov[2] = nv[2] * cv0 + nv[0] * sv0;
        ov[3] = nv[3] * cv1 + nv[1] * sv1;
        int tloc = q * 16 + lg * 4;
#pragma unroll
        for (int n = 0; n < 4; ++n)
#pragma unroll
          for (int r = 0; r < 4; ++r)
            tb[(tloc + r) * 76 + n * 16 + l15] = f2bf(ov[n][r]);
      }
      MEMBAR();                               // per-wave LDS in-order
      const int t = lane;
      unsigned short* yp = outp + ((size_t)bh * 2048 + tl + chunk * 64 + t) * 64;
#pragma unroll
      for (int j = 0; j < 8; ++j)
        *(bf16x8*)(yp + j * 8) = *(const bf16x8*)(tb + t * 76 + j * 8);
      MEMBAR();                               // bounce reads before next chunk's writes
    }
  } else {
#pragma unroll
    for (int chunk = 0; chunk < 2; ++chunk) {
#pragma unroll
      for (int q = 0; q < 4; ++q) {
        const int m = chunk * 4 + q;
#pragma unroll
        for (int n = 0; n < 4; ++n) {
          int d = n * 16 + l15, tloc = q * 16 + lg * 4;
          ushort4 pk;
          pk.x = f2bf(acc[m][n][0]); pk.y = f2bf(acc[m][n][1]);
          pk.z = f2bf(acc[m][n][2]); pk.w = f2bf(acc[m][n][3]);
          *(ushort4*)(tb + d * 76 + tloc) = pk;
        }
      }
      MEMBAR();
      int d2 = lane;
      unsigned short* vp = Vtg + ((size_t)bh * 64 + d2) * 2048 + tl + chunk * 64;
#pragma unroll
      for (int j = 0; j < 8; ++j) {
        bf16x8 vv = *(const bf16x8*)(tb + d2 * 76 + j * 8);
        *(bf16x8*)(vp + j * 8) = vv;
      }
      MEMBAR();
    }
  }
}

// ---------------- causal flash attention: QBLK=64, counted-vmcnt no-drain loop -------
// (R15 version, verified, best measured)
__global__ __launch_bounds__(256) void attn_fwd(const unsigned short* __restrict__ Q,
                                                const unsigned short* __restrict__ K,
                                                const unsigned short* __restrict__ Vtg,
                                                unsigned short* __restrict__ Y) {
  const int bh = blockIdx.x;        // 0..63
  const int pr = blockIdx.y;        // 0..15
  const int b = bh >> 4, h = bh & 15;
  const int tid = threadIdx.x;
  const int w = tid >> 6, lane = tid & 63;
  const int l15 = lane & 15, lg = lane >> 4;

  __shared__ unsigned short Kl[2][64 * 64];   // swizzled [k][d], 128B rows (16384 B)
  __shared__ unsigned short Vt[2][64 * 64];   // swizzled [d][k], 128B rows (16384 B)
  __shared__ unsigned short Pl[4][16 * 64];   // per-wave P^T [q][k], 128B rows, swz (8192 B)

  const size_t bhT = (size_t)bh * 2048;
  const char* Kg = (const char*)(K + bhT * 64);          // row stride 128B
  const char* Vg = (const char*)(Vtg + bhT * 64);        // row stride 4096B

  auto stage = [&](int buf, int kt) {
#pragma unroll
    for (int i = 0; i < 2; ++i) {
      int c = w * 2 + i;                     // chunk 0..7, wave-uniform
      int pos = c * 1024 + lane * 16;        // linear byte in 8KB tile
      int row = pos >> 7, cb = pos & 127;
      int srcb = cb ^ ((row & 7) << 4);      // inverse-swizzled source
      llds16(Kg + ((size_t)(kt * 64 + row)) * 128 + srcb,
             (char*)&Kl[buf][0] + c * 1024);
      llds16(Vg + (size_t)row * 4096 + (size_t)kt * 128 + srcb,
             (char*)&Vt[buf][0] + c * 1024);
    }
  };

  auto run_qtile = [&](int qtb) {
    const int qbase = qtb * 64;
    const unsigned short* Qp = Q + (bhT + qbase + w * 16 + l15) * 64 + lg * 8;
    bf16x8 aq[2];
    aq[0] = *(const bf16x8*)(Qp);
    aq[1] = *(const bf16x8*)(Qp + 32);

    f32x4 o[4] = {};        // O^T: lane q=l15, rows d = df*16 + lg*4 + r
    float psum = 0.0f;      // per-lane (q = l15) partial sum over its k slice

    char* Pw = (char*)&Pl[w][0];
    const int psw = (l15 & 7) << 4;       // 16B-granular XOR swizzle keyed by q-row

    for (int kt = 0; kt <= qtb; ++kt) {
      const int cur = kt & 1;
      if (kt < qtb) {
        stage(cur ^ 1, kt + 1);           // issue next tile: my 4 loads
        asm volatile("s_waitcnt vmcnt(4)" ::: "memory");   // wait MY tile-t loads
      } else {
        asm volatile("s_waitcnt vmcnt(0)" ::: "memory");   // final iter: drain
      }
      __builtin_amdgcn_s_barrier();       // all waves' tile-t loads now visible
      MEMBAR();
      const char* Kc = (const char*)&Kl[cur][0];
      const char* Vc = (const char*)&Vt[cur][0];

      f32x4 s[4] = {};      // S^T: lane q=l15, rows k = n*16 + lg*4 + r
      __builtin_amdgcn_s_setprio(1);
#pragma unroll
      for (int n = 0; n < 4; ++n) {
        int r = n * 16 + l15, sw = (r & 7) << 4;
#pragma unroll
        for (int ks = 0; ks < 2; ++ks) {
          bf16x8 bk = *(const bf16x8*)(Kc + r * 128 + ((ks * 64 + lg * 16) ^ sw));
          s[n] = __builtin_amdgcn_mfma_f32_16x16x32_bf16(bk, aq[ks], s[n], 0, 0, 0);
        }
      }
      __builtin_amdgcn_s_setprio(0);

      if (kt == qtb) {   // diagonal tile: causal mask (k_local > q_local)
#pragma unroll
        for (int n = 0; n < 4; ++n)
#pragma unroll
          for (int r = 0; r < 4; ++r)
            if (n * 16 + lg * 4 + r > w * 16 + l15) s[n][r] = -1e30f;
      }

      // p = exp2(s); per-lane psum; truncation-pack pairs -> b64 LDS writes
#pragma unroll
      for (int n = 0; n < 4; ++n) {
        float p0 = __builtin_exp2f(s[n][0]);
        float p1 = __builtin_exp2f(s[n][1]);
        float p2 = __builtin_exp2f(s[n][2]);
        float p3 = __builtin_exp2f(s[n][3]);
        psum += (p0 + p1) + (p2 + p3);
        unsigned u0 = __builtin_bit_cast(unsigned, p0);
        unsigned u1 = __builtin_bit_cast(unsigned, p1);
        unsigned u2 = __builtin_bit_cast(unsigned, p2);
        unsigned u3 = __builtin_bit_cast(unsigned, p3);
        uint2 pk;
        pk.x = (u0 >> 16) | (u1 & 0xffff0000u);
        pk.y = (u2 >> 16) | (u3 & 0xffff0000u);
        *(uint2*)(Pw + l15 * 128 + ((n * 32 + lg * 8) ^ psw)) = pk;
      }
      MEMBAR();  // keep P stores before P reads (per-wave LDS in-order)

      bf16x8 ap[2];
      ap[0] = *(const bf16x8*)(Pw + l15 * 128 + ((lg * 16) ^ psw));
      ap[1] = *(const bf16x8*)(Pw + l15 * 128 + ((64 + lg * 16) ^ psw));

      __builtin_amdgcn_s_setprio(1);
#pragma unroll
      for (int df = 0; df < 4; ++df) {
        int rr = df * 16 + l15, sw = (rr & 7) << 4;
#pragma unroll
        for (int ks = 0; ks < 2; ++ks) {
          bf16x8 bv = *(const bf16x8*)(Vc + rr * 128 + ((ks * 64 + lg * 16) ^ sw));
          o[df] = __builtin_amdgcn_mfma_f32_16x16x32_bf16(bv, ap[ks], o[df], 0, 0, 0);
        }
      }
      __builtin_amdgcn_s_setprio(0);
      MEMBAR();
      __builtin_amdgcn_s_barrier();       // all waves done reading before restage
      MEMBAR();
    }

    // full row-sum: combine the 4 lanes sharing this q (lg differs in bits 4..5)
    psum += __shfl_xor(psum, 16);
    psum += __shfl_xor(psum, 32);
    float inv = 1.0f / psum;

    size_t q = qbase + w * 16 + l15;
    unsigned short* yp = Y + ((size_t)b * 2048 + q) * 1024 + h * 64 + lg * 4;
#pragma unroll
    for (int df = 0; df < 4; ++df) {
      ushort4 v;
      v.x = f2bf(o[df][0] * inv);
      v.y = f2bf(o[df][1] * inv);
      v.z = f2bf(o[df][2] * inv);
      v.w = f2bf(o[df][3] * inv);
      *(ushort4*)(yp + df * 16) = v;
    }
  };

  // heavy segment then light segment; every block: 33 kv-tile iterations total
  stage(0, 0);
  run_qtile(31 - pr);
  stage(0, 0);
  run_qtile(pr);
}

// ---------------- launch ----------------
extern "C" void kernel_launch(void* const* d_in, const int* in_sizes, int n_in,
                              void* d_out, int out_size, void* d_ws, size_t ws_size,
                              hipStream_t stream) {
  const float* x = (const float*)d_in[0];
  const float* Wqkv = (const float*)d_in[1];
  const float* Wproj = (const float*)d_in[2];
  const float* qw = (const float*)d_in[3];
  const float* kw = (const float*)d_in[4];
  float* out = (float*)d_out;

  char* ws = (char*)d_ws;
  unsigned short* xb = (unsigned short*)ws;        ws += (size_t)8192 * 1024 * 2;
  unsigned short* wqkvt = (unsigned short*)ws;     ws += (size_t)3072 * 1024 * 2;
  unsigned short* wprojt = (unsigned short*)ws;    ws += (size_t)1024 * 1024 * 2;
  unsigned short* Qr = (unsigned short*)ws;        ws += (size_t)64 * 2048 * 64 * 2;
  unsigned short* Kr = (unsigned short*)ws;        ws += (size_t)64 * 2048 * 64 * 2;
  unsigned short* Vtg = (unsigned short*)ws;       ws += (size_t)64 * 64 * 2048 * 2;
  unsigned short* yb = (unsigned short*)ws;        ws += (size_t)8192 * 1024 * 2;
  float* cosTT = (float*)ws;                       ws += (size_t)32 * 2048 * 4;
  float* sinTT = (float*)ws;                       ws += (size_t)32 * 2048 * 4;

  prep_fused<<<3328, 256, 0, stream>>>(x, Wqkv, Wproj, xb, wqkvt, wprojt, cosTT, sinTT);
  gemm_qkvW<<<dim3(24, 32), 256, 0, stream>>>(xb, wqkvt, qw, kw, cosTT, sinTT, Qr, Kr, Vtg);
  attn_fwd<<<dim3(64, 16), 256, 0, stream>>>(Qr, Kr, Vtg, yb);
  gemm_ring<float><<<dim3(8, 64), 256, 0, stream>>>(yb, wprojt, out, 8192, 1024, 1024);
}